// Round 6
// baseline (309.962 us; speedup 1.0000x reference)
//
#include <hip/hip_runtime.h>
#include <math.h>
#include <stdint.h>

typedef __bf16 bf16;
typedef __bf16 bf16x2 __attribute__((ext_vector_type(2)));
typedef __bf16 bf16x4 __attribute__((ext_vector_type(4)));
typedef __bf16 bf16x8 __attribute__((ext_vector_type(8)));
typedef float f32x4 __attribute__((ext_vector_type(4)));
typedef float f32x16 __attribute__((ext_vector_type(16)));

constexpr int E = 1024;   // embed dim
constexpr int S = 2048;   // seq len
constexpr int H = 16;     // heads (Dh = 64)

// Fragment layouts (1KB blocks, lane l = hf*32 + ln, 16B per lane):
//  Q/K frag: per (b,h): block (t, c), t = s/32 (64), c = d-chunk/16 (4).
//    lane l = hf*32 + (s%32); bytes = X[s][c*16 + hf*8 + j], j=0..7.
//    elem addr = (bh*256 + t*4 + c)*512 + l*8 + j        (131072 elems per bh)
//    => a 32-s K tile t is elems [t*2048, t*2048+2048): 4KB contiguous.
//  V frag: per (b,h): block (tau, mt, c), tau = s/64 (32), mt = d/32 (2),
//    c = s-chunk-in-tile/16 (4). lane l = hf*32 + (d%32);
//    bytes = V^T[d][tau*64 + c*16 + hf*8 + j].
//    elem addr = (bh*256 + tau*8 + mt*4 + c)*512 + l*8 + j
//    => a 32-kv chunk (parity p in tile tau) = pieces (tau*8+mt*4+p*2)*512,
//       1024 elems each (c = p*2, p*2+1), per mt: 2 x 2KB.

// async global->LDS, 16B per lane; LDS dst = wave-uniform base + lane*16
__device__ __forceinline__ void gload16(const void* g, void* l) {
  __builtin_amdgcn_global_load_lds(
      (__attribute__((address_space(1))) void*)(uintptr_t)g,
      (__attribute__((address_space(3))) void*)(uint32_t)(uintptr_t)l, 16, 0, 0);
}

__device__ __forceinline__ f32x4 mfma16(bf16x8 a, bf16x8 b, f32x4 c) {
  return __builtin_amdgcn_mfma_f32_16x16x32_bf16(a, b, c, 0, 0, 0);
}
__device__ __forceinline__ f32x16 mfma32(bf16x8 a, bf16x8 b, f32x16 c) {
  return __builtin_amdgcn_mfma_f32_32x32x16_bf16(a, b, c, 0, 0, 0);
}

// native 2^x: ONE v_exp_f32. NOT exp2f (libm __ocml_exp2_f32, ~10 VALU ops —
// that bloat was R1's 59% VALUBusy regression).
__device__ __forceinline__ float fexp2(float x) {
#if __has_builtin(__builtin_amdgcn_exp2f)
  return __builtin_amdgcn_exp2f(x);
#else
  float r;
  asm("v_exp_f32 %0, %1" : "=v"(r) : "v"(x));
  return r;
#endif
}

// pack 2 f32 -> u32 of 2 bf16 (compiler emits v_cvt_pk_bf16_f32)
__device__ __forceinline__ uint32_t pkbf(float lo, float hi) {
  bf16x2 p;
  p[0] = (bf16)lo;
  p[1] = (bf16)hi;
  return __builtin_bit_cast(uint32_t, p);
}

// ---------------------------------------------------------------------------
// cast x (fp32) -> bf16, 8 elems/thread
// ---------------------------------------------------------------------------
__global__ __launch_bounds__(256) void cast_x(const float* __restrict__ x,
                                              bf16* __restrict__ o) {
  const size_t i = ((size_t)blockIdx.x * 256 + threadIdx.x) * 8;
  const float4 a = *(const float4*)(x + i);
  const float4 b = *(const float4*)(x + i + 4);
  bf16x8 r;
  r[0] = (bf16)a.x; r[1] = (bf16)a.y; r[2] = (bf16)a.z; r[3] = (bf16)a.w;
  r[4] = (bf16)b.x; r[5] = (bf16)b.y; r[6] = (bf16)b.z; r[7] = (bf16)b.w;
  *(bf16x8*)(o + i) = r;
}

// ---------------------------------------------------------------------------
// W[k][n] fp32 -> Wt[n][k] bf16 (all 4 weight matrices, blockIdx.z selects)
// ---------------------------------------------------------------------------
__global__ __launch_bounds__(256) void transpose_cast_w(
    const float* __restrict__ W0, const float* __restrict__ W1,
    const float* __restrict__ W2, const float* __restrict__ W3,
    bf16* __restrict__ T0, bf16* __restrict__ T1, bf16* __restrict__ T2,
    bf16* __restrict__ T3) {
  const float* W;
  bf16* T;
  switch (blockIdx.z) {
    case 0: W = W0; T = T0; break;
    case 1: W = W1; T = T1; break;
    case 2: W = W2; T = T2; break;
    default: W = W3; T = T3; break;
  }
  __shared__ float t[64][65];
  const int k0 = blockIdx.y * 64, n0 = blockIdx.x * 64;
  const int tr = threadIdx.x >> 4;          // 0..15
  const int tc = (threadIdx.x & 15) * 4;    // 0..60
#pragma unroll
  for (int u = 0; u < 4; ++u) {
    const float4 v = *(const float4*)(W + (size_t)(k0 + tr + u * 16) * E + n0 + tc);
    t[tr + u * 16][tc + 0] = v.x;
    t[tr + u * 16][tc + 1] = v.y;
    t[tr + u * 16][tc + 2] = v.z;
    t[tr + u * 16][tc + 3] = v.w;
  }
  __syncthreads();
#pragma unroll
  for (int u = 0; u < 4; ++u) {
    const int n = tr + u * 16;
    bf16x4 o;
#pragma unroll
    for (int i = 0; i < 4; ++i) o[i] = (bf16)t[tc + i][n];
    *(bf16x4*)(T + (size_t)(n0 + n) * E + k0 + tc) = o;
  }
}

// ---------------------------------------------------------------------------
// Fused QKV GEMM -> MFMA-frag-layout outputs. z selects {Wq->Qf, Wk->Kf,
// Wv->Vf}. 128x128 tile, BK=32, m97 staging. z==0 scales by 0.125*log2(e)
// (softmax uses native exp2 directly: 2^(s*log2e) == e^s).
// Grid (8, 32, 3) = 768 blocks = 3/CU.
// ---------------------------------------------------------------------------
__global__ __launch_bounds__(256) void gemm_qkv(const bf16* __restrict__ A,
                                                const bf16* __restrict__ Wt,
                                                const float* __restrict__ bq,
                                                const float* __restrict__ bk,
                                                const float* __restrict__ bv,
                                                bf16* __restrict__ qo,
                                                bf16* __restrict__ ko,
                                                bf16* __restrict__ vo) {
  __shared__ __attribute__((aligned(16))) bf16 Asm[128 * 32];
  __shared__ __attribute__((aligned(16))) bf16 Bsm[128 * 32];
  const int z = blockIdx.z;
  const bf16* Bt = Wt + (size_t)z * E * E;
  const float* bias = (z == 0) ? bq : (z == 1) ? bk : bv;
  const int tid = threadIdx.x;
  const int w = tid >> 6, lane = tid & 63, quad = lane >> 4, ln = lane & 15;
  const int bm = blockIdx.y * 128, bn = blockIdx.x * 128;
  const int wr = w >> 1, wc = w & 1;
  const int srow = w * 32 + (lane >> 2);
  const int scol = (lane & 3) * 8;
  const bf16* Ag = A + (size_t)(bm + srow) * E + scol;
  const bf16* Bg = Bt + (size_t)(bn + srow) * E + scol;
  f32x4 acc[4][4] = {};

  for (int k0 = 0; k0 < E; k0 += 32) {
    gload16(Ag + k0, &Asm[(w * 32) * 32]);
    gload16(Ag + k0 + (size_t)16 * E, &Asm[(w * 32 + 16) * 32]);
    gload16(Bg + k0, &Bsm[(w * 32) * 32]);
    gload16(Bg + k0 + (size_t)16 * E, &Bsm[(w * 32 + 16) * 32]);
    __syncthreads();
    bf16x8 af[4], bfr[4];
#pragma unroll
    for (int t = 0; t < 4; ++t) {
      af[t] = *(const bf16x8*)&Asm[(wr * 64 + t * 16 + ln) * 32 + quad * 8];
      bfr[t] = *(const bf16x8*)&Bsm[(wc * 64 + t * 16 + ln) * 32 + quad * 8];
    }
#pragma unroll
    for (int rt = 0; rt < 4; ++rt)
#pragma unroll
      for (int ct = 0; ct < 4; ++ct)
        acc[rt][ct] = mfma16(af[rt], bfr[ct], acc[rt][ct]);
    __syncthreads();
  }

  // 0.125 * log2(e) = 0.18033688011112042
  const float scl = (z == 0) ? 0.18033688f : 1.0f;
  const int hglob = (bn + wc * 64) >> 6;  // head (wave col-group = one head)
  float bvv[4];
#pragma unroll
  for (int ct = 0; ct < 4; ++ct) bvv[ct] = bias[bn + wc * 64 + ct * 16 + ln];

#pragma unroll
  for (int rt = 0; rt < 4; ++rt) {
    const int row0 = bm + wr * 64 + rt * 16 + quad * 4;
    const int bb = row0 >> 11;        // batch (tiles never span: 2048%128==0)
    const int rl = row0 & 2047;       // seq within batch
    const size_t hb = (size_t)(bb * 16 + hglob) * 131072;
#pragma unroll
    for (int ct = 0; ct < 4; ++ct) {
      if (z == 2) {
        // V frag: d = ct*16+ln -> mt = ct>>1, ln32 = (ct&1)*16+ln;
        // s = row0 -> tau = rl>>6, hf = (rl>>3)&1, j0 = rl&7 (r gives j0..j0+3)
        const int mt = ct >> 1, ln32 = ((ct & 1) << 4) | ln;
        const int tau = rl >> 6, hfv = (rl >> 3) & 1, j0 = rl & 7;
        bf16x4 p;
#pragma unroll
        for (int r = 0; r < 4; ++r) p[r] = (bf16)(acc[rt][ct][r] + bvv[ct]);
        *(bf16x4*)&vo[hb + (size_t)((tau * 8 + mt * 4 + rt) * 512 +
                                    hfv * 256 + ln32 * 8 + j0)] = p;
      } else {
        // Q/K frag: s -> t = rl>>5, ln0 = rl&31 (+r); d = ct*16+ln ->
        // c = ct, hf = ln>>3, j = ln&7
        bf16* o = (z == 0) ? qo : ko;
        const int t = rl >> 5, ln0 = rl & 31;
        const size_t base =
            hb + (size_t)((t * 4 + ct) * 512 + (ln >> 3) * 256 + (ln & 7));
#pragma unroll
        for (int r = 0; r < 4; ++r)
          o[base + (ln0 + r) * 8] = (bf16)((acc[rt][ct][r] + bvv[ct]) * scl);
      }
    }
  }
}

// ---------------------------------------------------------------------------
// Output GEMM: C[4096][1024] fp32 = A @ Wt^T + bias. 64x128 tile -> 512 blocks.
// ---------------------------------------------------------------------------
__global__ __launch_bounds__(256) void gemm_wo(const bf16* __restrict__ A,
                                               const bf16* __restrict__ Bt,
                                               const float* __restrict__ bias,
                                               float* __restrict__ C) {
  __shared__ __attribute__((aligned(16))) bf16 Asm[64 * 32];
  __shared__ __attribute__((aligned(16))) bf16 Bsm[128 * 32];
  const int tid = threadIdx.x;
  const int w = tid >> 6, lane = tid & 63, quad = lane >> 4, ln = lane & 15;
  const int bm = blockIdx.y * 64, bn = blockIdx.x * 128;
  const int wr = w >> 1, wc = w & 1;
  const int sr = lane >> 2, sc = (lane & 3) * 8;
  const bf16* Ag = A + (size_t)(bm + w * 16 + sr) * E + sc;
  const bf16* Bg = Bt + (size_t)(bn + w * 32 + sr) * E + sc;
  f32x4 acc[2][4] = {};

  for (int k0 = 0; k0 < E; k0 += 32) {
    gload16(Ag + k0, &Asm[(w * 16) * 32]);
    gload16(Bg + k0, &Bsm[(w * 32) * 32]);
    gload16(Bg + k0 + (size_t)16 * E, &Bsm[(w * 32 + 16) * 32]);
    __syncthreads();
    bf16x8 af[2], bfr[4];
#pragma unroll
    for (int t = 0; t < 2; ++t)
      af[t] = *(const bf16x8*)&Asm[(wr * 32 + t * 16 + ln) * 32 + quad * 8];
#pragma unroll
    for (int t = 0; t < 4; ++t)
      bfr[t] = *(const bf16x8*)&Bsm[(wc * 64 + t * 16 + ln) * 32 + quad * 8];
#pragma unroll
    for (int rt = 0; rt < 2; ++rt)
#pragma unroll
      for (int ct = 0; ct < 4; ++ct)
        acc[rt][ct] = mfma16(af[rt], bfr[ct], acc[rt][ct]);
    __syncthreads();
  }

  float bvv[4];
#pragma unroll
  for (int ct = 0; ct < 4; ++ct) bvv[ct] = bias[bn + wc * 64 + ct * 16 + ln];
#pragma unroll
  for (int rt = 0; rt < 2; ++rt) {
    const int row0 = bm + wr * 32 + rt * 16 + quad * 4;
#pragma unroll
    for (int ct = 0; ct < 4; ++ct) {
      const int c = bn + wc * 64 + ct * 16 + ln;
#pragma unroll
      for (int r = 0; r < 4; ++r)
        C[(size_t)(row0 + r) * E + c] = acc[rt][ct][r] + bvv[ct];
    }
  }
}

// ---------------------------------------------------------------------------
// MFMA flash attention v12: occupancy 2x via 16-wave blocks.
// R5 pipe accounting at 16 waves/CU: LDS-pipe busy ~20.5us (48%) > VALU 16
// (37%) > MFMA 13.7 (32%) — latency/overlap-bound, and total LDS reads are
// INVARIANT to geometry (2048 q-waves x 256 b128). The lever is waves/CU:
// 1024 thr = 16 waves (4 qi x 4 ki), KVBLK=32 -> LDS 2x32KB dbuf (+2KB
// combine) -> still 2 blk/CU but 32 waves/CU (100% occupancy, was 16).
// Per-wave inner iter is exactly half a v8 mt-pair (verbatim math): 4 K-frag
// b128, 4 QK mfma32, 16 exp2, pack/permlane, 4 V b128, 4 PV mfma32.
// Staging totals, FETCH, MFMA/VALU totals unchanged. VGPR must stay <=64
// (forced via __launch_bounds__(1024,8)) or 2-block residency is lost.
// Combine: 2-round in-LDS tree over 4 ki partials (deferred softmax = adds).
// ---------------------------------------------------------------------------
__global__ __launch_bounds__(1024, 8) void attn_mfma(
    const bf16* __restrict__ Qf, const bf16* __restrict__ Kf,
    const bf16* __restrict__ Vf, bf16* __restrict__ Og) {
  // main loop: buffer b at smem + b*32768 (16384 elems):
  //   K: 4 ki x 2048 elems; V at +8192 elems: 4 ki x 2048 ([mtv][half])
  // epilogue: Ocmb 8 slots x 8KB = 64KB at smem, Lcmb 8 x 64 f32 at +65536
  __shared__ __attribute__((aligned(16))) char smem[67584];

  const int tid = threadIdx.x;
  const int w = tid >> 6, lane = tid & 63, ln = lane & 31, hf = lane >> 5;
  const int qi = w & 3, ki = w >> 2;        // 4 q-tiles x 4 kv-quarters
  const int tq = blockIdx.x * 4 + qi;       // q-tile (32 q-rows)
  const int h = blockIdx.y, b = blockIdx.z;
  const size_t fb = (size_t)(b * H + h) * 131072;

  // Q B-frags once (B[k=d][n=q]): lane q = ln, d = c*16 + hf*8 + j
  bf16x8 qf[4];
  {
    const bf16* qb = Qf + fb + (size_t)tq * 2048 + lane * 8;
#pragma unroll
    for (int c = 0; c < 4; ++c) qf[c] = *(const bf16x8*)(qb + c * 512);
  }

  const bf16* Ksrc = Kf + fb + lane * 8;
  const bf16* Vsrc = Vf + fb + lane * 8;
  const int mtv = qi >> 1, half = qi & 1;   // this wave's V staging piece

  float lpart = 0.f;
  f32x16 oacc[2] = {};

  // per iter, ki-group stages its 32-kv chunk: K 4KB + V 4KB = 8 gloads
  // across 4 qi waves = 2 gloads/wave.
#define STAGE(i, buf)                                                        \
  do {                                                                       \
    const int t = ki * 16 + (i);                                             \
    bf16* base = (bf16*)smem + (buf) * 16384;                                \
    gload16(Ksrc + (size_t)t * 2048 + qi * 512,                              \
            base + ki * 2048 + qi * 512);                                    \
    gload16(Vsrc + (size_t)(((t >> 1) * 8 + mtv * 4 + ((i) & 1) * 2) * 512 + \
                            half * 512),                                     \
            base + 8192 + ki * 2048 + mtv * 1024 + half * 512);              \
  } while (0)

  STAGE(0, 0);
  __syncthreads();  // vmcnt(0)+barrier: chunk 0 staged

#pragma unroll 2
  for (int i = 0; i < 16; ++i) {
    const int cur = i & 1;
    if (i < 15) STAGE(i + 1, cur ^ 1);  // prefetch: latency hides under MFMA
    const bf16* Kc = (const bf16*)smem + cur * 16384 + ki * 2048;
    const bf16* Vc = Kc + 8192;

    // scores S^T (rows kv=32, cols q): A = K frags, B = qf
    f32x16 st = {};
    __builtin_amdgcn_s_setprio(1);
#pragma unroll
    for (int c = 0; c < 4; ++c)
      st = mfma32(*(const bf16x8*)&Kc[c * 512 + lane * 8], qf[c], st);
    __builtin_amdgcn_s_setprio(0);

    // P = 2^st (Q carries 0.125*log2e); C-layout kv = 8g + 4hf + j
    float pe[16];
#pragma unroll
    for (int r = 0; r < 16; ++r) pe[r] = fexp2(st[r]);
    // tree-reduce row-sum (short dep chain)
    lpart += (((pe[0] + pe[1]) + (pe[2] + pe[3])) +
              ((pe[4] + pe[5]) + (pe[6] + pe[7]))) +
             (((pe[8] + pe[9]) + (pe[10] + pe[11])) +
              ((pe[12] + pe[13]) + (pe[14] + pe[15])));

    // Build PV B-frags in-register (T12). Target (chunk cl): lane(hf,ln)
    // needs kv = cl*16 + hf*8 + j at q=ln. Own regs give 8g+4hf+j; the
    // missing half lives at lane^32 -> one permlane32_swap fills two words.
    bf16x8 pb[2];
#pragma unroll
    for (int cl = 0; cl < 2; ++cl) {
      uint32_t a01 = pkbf(pe[cl * 8 + 0], pe[cl * 8 + 1]);
      uint32_t a23 = pkbf(pe[cl * 8 + 2], pe[cl * 8 + 3]);
      uint32_t b01 = pkbf(pe[cl * 8 + 4], pe[cl * 8 + 5]);
      uint32_t b23 = pkbf(pe[cl * 8 + 6], pe[cl * 8 + 7]);
      auto r0 = __builtin_amdgcn_permlane32_swap(a01, b01, false, false);
      auto r1 = __builtin_amdgcn_permlane32_swap(a23, b23, false, false);
      union {
        bf16x8 v;
        uint32_t u[4];
      } pu;
      pu.u[0] = r0[0];
      pu.u[1] = r1[0];
      pu.u[2] = r0[1];
      pu.u[3] = r1[1];
      pb[cl] = pu.v;
    }

    // O^T += V^T . P^T  (A = V frags [vt d-half][cl kv-chunk])
    __builtin_amdgcn_s_setprio(1);
#pragma unroll
    for (int vt = 0; vt < 2; ++vt) {
      oacc[vt] = mfma32(*(const bf16x8*)&Vc[vt * 1024 + lane * 8], pb[0],
                        oacc[vt]);
      oacc[vt] = mfma32(*(const bf16x8*)&Vc[vt * 1024 + 512 + lane * 8], pb[1],
                        oacc[vt]);
    }
    __builtin_amdgcn_s_setprio(0);

    __syncthreads();  // reads retired + next chunk's gloads drained
  }
#undef STAGE

  // ---- 4-way ki combine (deferred softmax => partials just add) ----
  float* Oc = (float*)smem;              // 8 slots x 32 x 64 f32
  float* Lc = (float*)(smem + 65536);    // 8 slots x 64 f32
  if (ki >= 2) {
    const int s = qi * 2 + (ki - 2);
#pragma unroll
    for (int vt = 0; vt < 2; ++vt)
#pragma unroll
      for (int r = 0; r < 16; ++r)
        Oc[s * 2048 + (vt * 16 + r) * 64 + lane] = oacc[vt][r];
    Lc[s * 64 + lane] = lpart;
  }
  __syncthreads();
  if (ki < 2) {
    const int s = qi * 2 + ki;
#pragma unroll
    for (int vt = 0; vt < 2; ++vt)
#pragma unroll
      for (int r = 0; r < 16; ++r)
        oacc[vt][r] += Oc[s * 2048 + (vt * 16 + r) * 64 + lane];
    lpart += Lc[s * 64 + lane];
  }
  __syncthreads();  // WAR: round-A reads done before round-B rewrite
  if (ki == 1) {
    const int s = qi * 2;
#pragma unroll
    for (int vt = 0; vt < 2; ++vt)
#pragma unroll
      for (int r = 0; r < 16; ++r)
        Oc[s * 2048 + (vt * 16 + r) * 64 + lane] = oacc[vt][r];
    Lc[s * 64 + lane] = lpart;
  }
  __syncthreads();
  if (ki == 0) {
    const int s = qi * 2;
#pragma unroll
    for (int vt = 0; vt < 2; ++vt)
#pragma unroll
      for (int r = 0; r < 16; ++r)
        oacc[vt][r] += Oc[s * 2048 + (vt * 16 + r) * 64 + lane];
    lpart += Lc[s * 64 + lane];

    // lane-halves hold disjoint kv subsets of the same q
    lpart += __shfl_xor(lpart, 32);
    const float inv = 1.0f / lpart;

    // O^T C-layout: q = ln, d = vt*32 + g*8 + hf*4 + j; Og row-major [s][E]
    bf16* orow = Og + ((size_t)b * S + (size_t)tq * 32 + ln) * E + h * 64;
#pragma unroll
    for (int vt = 0; vt < 2; ++vt) {
#pragma unroll
      for (int g = 0; g < 4; ++g) {
        bf16x4 o;
#pragma unroll
        for (int j = 0; j < 4; ++j) o[j] = (bf16)(oacc[vt][g * 4 + j] * inv);
        *(bf16x4*)&orow[vt * 32 + g * 8 + hf * 4] = o;
      }
    }
  }
}

// ---------------------------------------------------------------------------
extern "C" void kernel_launch(void* const* d_in, const int* in_sizes, int n_in,
                              void* d_out, int out_size, void* d_ws, size_t ws_size,
                              hipStream_t stream) {
  const float* x = (const float*)d_in[0];
  const float* Wq = (const float*)d_in[1];
  const float* bq = (const float*)d_in[2];
  const float* Wk = (const float*)d_in[3];
  const float* bk = (const float*)d_in[4];
  const float* Wv = (const float*)d_in[5];
  const float* bv = (const float*)d_in[6];
  const float* Wo = (const float*)d_in[7];
  const float* bo = (const float*)d_in[8];

  const size_t ME = (size_t)4096 * 1024;  // 4M elems
  const size_t WE = (size_t)1024 * 1024;  // 1M elems
  bf16* xb = (bf16*)d_ws;
  bf16* wqt = xb + ME;
  bf16* wkt = wqt + WE;
  bf16* wvt = wkt + WE;
  bf16* wot = wvt + WE;
  bf16* qb = wot + WE;   // Q frags
  bf16* kb = qb + ME;    // K frags
  bf16* vt = kb + ME;    // V frags
  bf16* ab = vt + ME;    // attn out, row-major [B*S][E]

  cast_x<<<2048, 256, 0, stream>>>(x, xb);
  transpose_cast_w<<<dim3(16, 16, 4), 256, 0, stream>>>(Wq, Wk, Wv, Wo, wqt, wkt,
                                                        wvt, wot);
  gemm_qkv<<<dim3(8, 32, 3), 256, 0, stream>>>(xb, wqt, bq, bk, bv, qb, kb, vt);
  attn_mfma<<<dim3(S / 128, H, 2), 1024, 0, stream>>>(qb, kb, vt, ab);
  gemm_wo<<<dim3(8, 64), 256, 0, stream>>>(ab, wot, bo, (float*)d_out);
}

// Round 7
// 269.396 us; speedup vs baseline: 1.1506x; 1.1506x over previous
//
#include <hip/hip_runtime.h>
#include <math.h>
#include <stdint.h>

typedef __bf16 bf16;
typedef __bf16 bf16x2 __attribute__((ext_vector_type(2)));
typedef __bf16 bf16x4 __attribute__((ext_vector_type(4)));
typedef __bf16 bf16x8 __attribute__((ext_vector_type(8)));
typedef float f32x4 __attribute__((ext_vector_type(4)));
typedef float f32x16 __attribute__((ext_vector_type(16)));

constexpr int E = 1024;   // embed dim
constexpr int S = 2048;   // seq len
constexpr int H = 16;     // heads (Dh = 64)

// Fragment layouts (1KB blocks, lane l = hf*32 + ln, 16B per lane):
//  Q/K frag: per (b,h): block (t, c), t = s/32 (64), c = d-chunk/16 (4).
//    lane l = hf*32 + (s%32); bytes = X[s][c*16 + hf*8 + j], j=0..7.
//    elem addr = (bh*256 + t*4 + c)*512 + l*8 + j        (131072 elems per bh)
//    => a 32-s K tile t is elems [t*2048, t*2048+2048): 4KB contiguous.
//  V frag: per (b,h): block (tau, mt, c), tau = s/64 (32), mt = d/32 (2),
//    c = s-chunk-in-tile/16 (4). lane l = hf*32 + (d%32);
//    bytes = V^T[d][tau*64 + c*16 + hf*8 + j].
//    elem addr = (bh*256 + tau*8 + mt*4 + c)*512 + l*8 + j
//    => a 32-kv chunk (parity p of tile tau): per d-half mt the 2 pieces
//       (tau*8 + mt*4 + p*2 + c)*512, c in {0,1}.

// async global->LDS, 16B per lane; LDS dst = wave-uniform base + lane*16
__device__ __forceinline__ void gload16(const void* g, void* l) {
  __builtin_amdgcn_global_load_lds(
      (__attribute__((address_space(1))) void*)(uintptr_t)g,
      (__attribute__((address_space(3))) void*)(uint32_t)(uintptr_t)l, 16, 0, 0);
}

__device__ __forceinline__ f32x4 mfma16(bf16x8 a, bf16x8 b, f32x4 c) {
  return __builtin_amdgcn_mfma_f32_16x16x32_bf16(a, b, c, 0, 0, 0);
}
__device__ __forceinline__ f32x16 mfma32(bf16x8 a, bf16x8 b, f32x16 c) {
  return __builtin_amdgcn_mfma_f32_32x32x16_bf16(a, b, c, 0, 0, 0);
}

// native 2^x: ONE v_exp_f32. NOT exp2f (libm __ocml_exp2_f32, ~10 VALU ops —
// that bloat was R1's 59% VALUBusy regression).
__device__ __forceinline__ float fexp2(float x) {
#if __has_builtin(__builtin_amdgcn_exp2f)
  return __builtin_amdgcn_exp2f(x);
#else
  float r;
  asm("v_exp_f32 %0, %1" : "=v"(r) : "v"(x));
  return r;
#endif
}

// pack 2 f32 -> u32 of 2 bf16 (compiler emits v_cvt_pk_bf16_f32)
__device__ __forceinline__ uint32_t pkbf(float lo, float hi) {
  bf16x2 p;
  p[0] = (bf16)lo;
  p[1] = (bf16)hi;
  return __builtin_bit_cast(uint32_t, p);
}

// ---------------------------------------------------------------------------
// cast x (fp32) -> bf16, 8 elems/thread
// ---------------------------------------------------------------------------
__global__ __launch_bounds__(256) void cast_x(const float* __restrict__ x,
                                              bf16* __restrict__ o) {
  const size_t i = ((size_t)blockIdx.x * 256 + threadIdx.x) * 8;
  const float4 a = *(const float4*)(x + i);
  const float4 b = *(const float4*)(x + i + 4);
  bf16x8 r;
  r[0] = (bf16)a.x; r[1] = (bf16)a.y; r[2] = (bf16)a.z; r[3] = (bf16)a.w;
  r[4] = (bf16)b.x; r[5] = (bf16)b.y; r[6] = (bf16)b.z; r[7] = (bf16)b.w;
  *(bf16x8*)(o + i) = r;
}

// ---------------------------------------------------------------------------
// W[k][n] fp32 -> Wt[n][k] bf16 (all 4 weight matrices, blockIdx.z selects)
// ---------------------------------------------------------------------------
__global__ __launch_bounds__(256) void transpose_cast_w(
    const float* __restrict__ W0, const float* __restrict__ W1,
    const float* __restrict__ W2, const float* __restrict__ W3,
    bf16* __restrict__ T0, bf16* __restrict__ T1, bf16* __restrict__ T2,
    bf16* __restrict__ T3) {
  const float* W;
  bf16* T;
  switch (blockIdx.z) {
    case 0: W = W0; T = T0; break;
    case 1: W = W1; T = T1; break;
    case 2: W = W2; T = T2; break;
    default: W = W3; T = T3; break;
  }
  __shared__ float t[64][65];
  const int k0 = blockIdx.y * 64, n0 = blockIdx.x * 64;
  const int tr = threadIdx.x >> 4;          // 0..15
  const int tc = (threadIdx.x & 15) * 4;    // 0..60
#pragma unroll
  for (int u = 0; u < 4; ++u) {
    const float4 v = *(const float4*)(W + (size_t)(k0 + tr + u * 16) * E + n0 + tc);
    t[tr + u * 16][tc + 0] = v.x;
    t[tr + u * 16][tc + 1] = v.y;
    t[tr + u * 16][tc + 2] = v.z;
    t[tr + u * 16][tc + 3] = v.w;
  }
  __syncthreads();
#pragma unroll
  for (int u = 0; u < 4; ++u) {
    const int n = tr + u * 16;
    bf16x4 o;
#pragma unroll
    for (int i = 0; i < 4; ++i) o[i] = (bf16)t[tc + i][n];
    *(bf16x4*)(T + (size_t)(n0 + n) * E + k0 + tc) = o;
  }
}

// ---------------------------------------------------------------------------
// Fused QKV GEMM -> MFMA-frag-layout outputs. z selects {Wq->Qf, Wk->Kf,
// Wv->Vf}. 128x128 tile, BK=32, m97 staging. z==0 scales by 0.125*log2(e)
// (softmax uses native exp2 directly: 2^(s*log2e) == e^s).
// Grid (8, 32, 3) = 768 blocks = 3/CU.
// ---------------------------------------------------------------------------
__global__ __launch_bounds__(256) void gemm_qkv(const bf16* __restrict__ A,
                                                const bf16* __restrict__ Wt,
                                                const float* __restrict__ bq,
                                                const float* __restrict__ bk,
                                                const float* __restrict__ bv,
                                                bf16* __restrict__ qo,
                                                bf16* __restrict__ ko,
                                                bf16* __restrict__ vo) {
  __shared__ __attribute__((aligned(16))) bf16 Asm[128 * 32];
  __shared__ __attribute__((aligned(16))) bf16 Bsm[128 * 32];
  const int z = blockIdx.z;
  const bf16* Bt = Wt + (size_t)z * E * E;
  const float* bias = (z == 0) ? bq : (z == 1) ? bk : bv;
  const int tid = threadIdx.x;
  const int w = tid >> 6, lane = tid & 63, quad = lane >> 4, ln = lane & 15;
  const int bm = blockIdx.y * 128, bn = blockIdx.x * 128;
  const int wr = w >> 1, wc = w & 1;
  const int srow = w * 32 + (lane >> 2);
  const int scol = (lane & 3) * 8;
  const bf16* Ag = A + (size_t)(bm + srow) * E + scol;
  const bf16* Bg = Bt + (size_t)(bn + srow) * E + scol;
  f32x4 acc[4][4] = {};

  for (int k0 = 0; k0 < E; k0 += 32) {
    gload16(Ag + k0, &Asm[(w * 32) * 32]);
    gload16(Ag + k0 + (size_t)16 * E, &Asm[(w * 32 + 16) * 32]);
    gload16(Bg + k0, &Bsm[(w * 32) * 32]);
    gload16(Bg + k0 + (size_t)16 * E, &Bsm[(w * 32 + 16) * 32]);
    __syncthreads();
    bf16x8 af[4], bfr[4];
#pragma unroll
    for (int t = 0; t < 4; ++t) {
      af[t] = *(const bf16x8*)&Asm[(wr * 64 + t * 16 + ln) * 32 + quad * 8];
      bfr[t] = *(const bf16x8*)&Bsm[(wc * 64 + t * 16 + ln) * 32 + quad * 8];
    }
#pragma unroll
    for (int rt = 0; rt < 4; ++rt)
#pragma unroll
      for (int ct = 0; ct < 4; ++ct)
        acc[rt][ct] = mfma16(af[rt], bfr[ct], acc[rt][ct]);
    __syncthreads();
  }

  // 0.125 * log2(e) = 0.18033688011112042
  const float scl = (z == 0) ? 0.18033688f : 1.0f;
  const int hglob = (bn + wc * 64) >> 6;  // head (wave col-group = one head)
  float bvv[4];
#pragma unroll
  for (int ct = 0; ct < 4; ++ct) bvv[ct] = bias[bn + wc * 64 + ct * 16 + ln];

#pragma unroll
  for (int rt = 0; rt < 4; ++rt) {
    const int row0 = bm + wr * 64 + rt * 16 + quad * 4;
    const int bb = row0 >> 11;        // batch (tiles never span: 2048%128==0)
    const int rl = row0 & 2047;       // seq within batch
    const size_t hb = (size_t)(bb * 16 + hglob) * 131072;
#pragma unroll
    for (int ct = 0; ct < 4; ++ct) {
      if (z == 2) {
        // V frag: d = ct*16+ln -> mt = ct>>1, ln32 = (ct&1)*16+ln;
        // s = row0 -> tau = rl>>6, hf = (rl>>3)&1, j0 = rl&7 (r gives j0..j0+3)
        const int mt = ct >> 1, ln32 = ((ct & 1) << 4) | ln;
        const int tau = rl >> 6, hfv = (rl >> 3) & 1, j0 = rl & 7;
        bf16x4 p;
#pragma unroll
        for (int r = 0; r < 4; ++r) p[r] = (bf16)(acc[rt][ct][r] + bvv[ct]);
        *(bf16x4*)&vo[hb + (size_t)((tau * 8 + mt * 4 + rt) * 512 +
                                    hfv * 256 + ln32 * 8 + j0)] = p;
      } else {
        // Q/K frag: s -> t = rl>>5, ln0 = rl&31 (+r); d = ct*16+ln ->
        // c = ct, hf = ln>>3, j = ln&7
        bf16* o = (z == 0) ? qo : ko;
        const int t = rl >> 5, ln0 = rl & 31;
        const size_t base =
            hb + (size_t)((t * 4 + ct) * 512 + (ln >> 3) * 256 + (ln & 7));
#pragma unroll
        for (int r = 0; r < 4; ++r)
          o[base + (ln0 + r) * 8] = (bf16)((acc[rt][ct][r] + bvv[ct]) * scl);
      }
    }
  }
}

// ---------------------------------------------------------------------------
// Output GEMM: C[4096][1024] fp32 = A @ Wt^T + bias. 64x128 tile -> 512 blocks.
// ---------------------------------------------------------------------------
__global__ __launch_bounds__(256) void gemm_wo(const bf16* __restrict__ A,
                                               const bf16* __restrict__ Bt,
                                               const float* __restrict__ bias,
                                               float* __restrict__ C) {
  __shared__ __attribute__((aligned(16))) bf16 Asm[64 * 32];
  __shared__ __attribute__((aligned(16))) bf16 Bsm[128 * 32];
  const int tid = threadIdx.x;
  const int w = tid >> 6, lane = tid & 63, quad = lane >> 4, ln = lane & 15;
  const int bm = blockIdx.y * 64, bn = blockIdx.x * 128;
  const int wr = w >> 1, wc = w & 1;
  const int sr = lane >> 2, sc = (lane & 3) * 8;
  const bf16* Ag = A + (size_t)(bm + w * 16 + sr) * E + sc;
  const bf16* Bg = Bt + (size_t)(bn + w * 32 + sr) * E + sc;
  f32x4 acc[2][4] = {};

  for (int k0 = 0; k0 < E; k0 += 32) {
    gload16(Ag + k0, &Asm[(w * 16) * 32]);
    gload16(Bg + k0, &Bsm[(w * 32) * 32]);
    gload16(Bg + k0 + (size_t)16 * E, &Bsm[(w * 32 + 16) * 32]);
    __syncthreads();
    bf16x8 af[2], bfr[4];
#pragma unroll
    for (int t = 0; t < 2; ++t)
      af[t] = *(const bf16x8*)&Asm[(wr * 32 + t * 16 + ln) * 32 + quad * 8];
#pragma unroll
    for (int t = 0; t < 4; ++t)
      bfr[t] = *(const bf16x8*)&Bsm[(wc * 64 + t * 16 + ln) * 32 + quad * 8];
#pragma unroll
    for (int rt = 0; rt < 2; ++rt)
#pragma unroll
      for (int ct = 0; ct < 4; ++ct)
        acc[rt][ct] = mfma16(af[rt], bfr[ct], acc[rt][ct]);
    __syncthreads();
  }

  float bvv[4];
#pragma unroll
  for (int ct = 0; ct < 4; ++ct) bvv[ct] = bias[bn + wc * 64 + ct * 16 + ln];
#pragma unroll
  for (int rt = 0; rt < 2; ++rt) {
    const int row0 = bm + wr * 32 + rt * 16 + quad * 4;
#pragma unroll
    for (int ct = 0; ct < 4; ++ct) {
      const int c = bn + wc * 64 + ct * 16 + ln;
#pragma unroll
      for (int r = 0; r < 4; ++r)
        C[(size_t)(row0 + r) * E + c] = acc[rt][ct][r] + bvv[ct];
    }
  }
}

// ---------------------------------------------------------------------------
// MFMA flash attention v13: R3's 2-MFMA-per-LDS-read ratio AT v8's 16
// waves/CU. Triangulation of R2/R3/R6:
//   v8 (42.6us): 16 w/CU, 1 ds_read per mfma  -> LDS-pipe-heavy.
//   R3 (47.7us): 2 mfma per ds_read but 8 w/CU -> TLP-starved.
//   R6 (166us):  forced <=64 VGPR -> spill.
// v13: 512 thr = 8 waves = 2 qi (64 q-rows, qg=2 subtiles) x 4 ki (512 kv),
// KVBLK=32/iter. LDS = 2 dbuf x (K 16KB + V 16KB) = 64KB -> 2 blk/CU ->
// 16 waves/CU at VGPR<=128 (R3 measured 116 for this per-wave state;
// __launch_bounds__(512,4) caps at 128, no forced spill).
// Per iter: 8 ds_read_b128 feed 16 mfma32 (ratio 2:1 — halves LDS pipe vs
// v8) + 32 exp2. Staging = R6's verified addresses (2 qi waves stage K
// chunks qi*2..+1 and V d-half mt=qi). Combine: R6's 2-round 8-slot tree.
// ---------------------------------------------------------------------------
__global__ __launch_bounds__(512, 4) void attn_mfma(
    const bf16* __restrict__ Qf, const bf16* __restrict__ Kf,
    const bf16* __restrict__ Vf, bf16* __restrict__ Og) {
  // main loop: buffer b at smem + b*32768 (16384 elems):
  //   K: 4 ki x 2048 elems; V at +8192 elems: 4 ki x 2048 ([mt][cl])
  // epilogue: Oc 8 slots x 8KB = 64KB, Lc 8 x 64 f32 at +65536
  __shared__ __attribute__((aligned(16))) char smem[67584];

  const int tid = threadIdx.x;
  const int w = tid >> 6, lane = tid & 63, ln = lane & 31, hf = lane >> 5;
  const int qi = w & 1, ki = w >> 1;        // 2 q-groups x 4 kv-quarters
  const int h = blockIdx.y, b = blockIdx.z;
  const size_t fb = (size_t)(b * H + h) * 131072;

  // Q B-frags for both 32-row subtiles: lane q = ln, d = c*16 + hf*8 + j
  bf16x8 qf[2][4];
#pragma unroll
  for (int qg = 0; qg < 2; ++qg) {
    const bf16* qb =
        Qf + fb + (size_t)(blockIdx.x * 4 + qi * 2 + qg) * 2048 + lane * 8;
#pragma unroll
    for (int c = 0; c < 4; ++c) qf[qg][c] = *(const bf16x8*)(qb + c * 512);
  }

  const bf16* Ksrc = Kf + fb + lane * 8;
  const bf16* Vsrc = Vf + fb + lane * 8;

  float lpart[2] = {0.f, 0.f};
  f32x16 oacc[2][2] = {};  // [qg][vt]

  // per iter, each ki-group stages its 32-kv chunk: K 4KB + V 4KB over its
  // 2 qi waves = 4 gloads/wave. K tile t: 4 x 512-elem chunks (wave qi takes
  // qi*2, qi*2+1). V: wave qi stages d-half mt=qi (2 pieces).
#define STAGE(i, buf)                                                       \
  do {                                                                      \
    const int t = ki * 16 + (i);                                            \
    const int tau = t >> 1, p = (i) & 1;                                    \
    bf16* base = (bf16*)smem + (buf) * 16384;                               \
    gload16(Ksrc + (size_t)t * 2048 + (qi * 2 + 0) * 512,                   \
            base + ki * 2048 + (qi * 2 + 0) * 512);                         \
    gload16(Ksrc + (size_t)t * 2048 + (qi * 2 + 1) * 512,                   \
            base + ki * 2048 + (qi * 2 + 1) * 512);                         \
    gload16(Vsrc + (size_t)(tau * 8 + qi * 4 + p * 2 + 0) * 512,            \
            base + 8192 + ki * 2048 + qi * 1024 + 0 * 512);                 \
    gload16(Vsrc + (size_t)(tau * 8 + qi * 4 + p * 2 + 1) * 512,            \
            base + 8192 + ki * 2048 + qi * 1024 + 1 * 512);                 \
  } while (0)

  STAGE(0, 0);
  __syncthreads();  // vmcnt(0)+barrier: chunk 0 staged

#pragma unroll 2
  for (int i = 0; i < 16; ++i) {
    const int cur = i & 1;
    if (i < 15) STAGE(i + 1, cur ^ 1);  // prefetch: latency hides under MFMA
    const bf16* Kc = (const bf16*)smem + cur * 16384 + ki * 2048;
    const bf16* Vc = (const bf16*)smem + cur * 16384 + 8192 + ki * 2048;

    // K frags once, reused for both qg (the LDS-ratio win)
    bf16x8 kf4[4];
#pragma unroll
    for (int c = 0; c < 4; ++c)
      kf4[c] = *(const bf16x8*)&Kc[c * 512 + lane * 8];

    // scores S^T (rows kv=32, cols q): two independent accumulator chains
    f32x16 st[2] = {{}, {}};
    __builtin_amdgcn_s_setprio(1);
#pragma unroll
    for (int c = 0; c < 4; ++c) {
      st[0] = mfma32(kf4[c], qf[0][c], st[0]);
      st[1] = mfma32(kf4[c], qf[1][c], st[1]);
    }
    __builtin_amdgcn_s_setprio(0);

    // P = 2^st (Q carries 0.125*log2e); C-layout kv = 8g + 4hf + j.
    // In-register P->B-frag (T12): one permlane32_swap fills two words.
    bf16x8 pb[2][2];
#pragma unroll
    for (int qg = 0; qg < 2; ++qg) {
      float pe[16];
#pragma unroll
      for (int r = 0; r < 16; ++r) pe[r] = fexp2(st[qg][r]);
      lpart[qg] += (((pe[0] + pe[1]) + (pe[2] + pe[3])) +
                    ((pe[4] + pe[5]) + (pe[6] + pe[7]))) +
                   (((pe[8] + pe[9]) + (pe[10] + pe[11])) +
                    ((pe[12] + pe[13]) + (pe[14] + pe[15])));
#pragma unroll
      for (int cl = 0; cl < 2; ++cl) {
        uint32_t a01 = pkbf(pe[cl * 8 + 0], pe[cl * 8 + 1]);
        uint32_t a23 = pkbf(pe[cl * 8 + 2], pe[cl * 8 + 3]);
        uint32_t b01 = pkbf(pe[cl * 8 + 4], pe[cl * 8 + 5]);
        uint32_t b23 = pkbf(pe[cl * 8 + 6], pe[cl * 8 + 7]);
        auto r0 = __builtin_amdgcn_permlane32_swap(a01, b01, false, false);
        auto r1 = __builtin_amdgcn_permlane32_swap(a23, b23, false, false);
        union {
          bf16x8 v;
          uint32_t u[4];
        } pu;
        pu.u[0] = r0[0];
        pu.u[1] = r1[0];
        pu.u[2] = r0[1];
        pu.u[3] = r1[1];
        pb[qg][cl] = pu.v;
      }
    }

    // V frags once, reused for both qg
    bf16x8 vf[2][2];  // [vt][cl]
#pragma unroll
    for (int vt = 0; vt < 2; ++vt)
#pragma unroll
      for (int cl = 0; cl < 2; ++cl)
        vf[vt][cl] = *(const bf16x8*)&Vc[vt * 1024 + cl * 512 + lane * 8];

    // O^T += V^T . P^T  (4 independent accumulator chains)
    __builtin_amdgcn_s_setprio(1);
#pragma unroll
    for (int qg = 0; qg < 2; ++qg)
#pragma unroll
      for (int vt = 0; vt < 2; ++vt) {
        oacc[qg][vt] = mfma32(vf[vt][0], pb[qg][0], oacc[qg][vt]);
        oacc[qg][vt] = mfma32(vf[vt][1], pb[qg][1], oacc[qg][vt]);
      }
    __builtin_amdgcn_s_setprio(0);

    __syncthreads();  // reads retired + next chunk's gloads drained
  }
#undef STAGE

  // ---- 4-way ki combine (deferred softmax => partials just add) ----
  float* Oc = (float*)smem;              // 8 slots x 32 x 64 f32
  float* Lc = (float*)(smem + 65536);    // 8 slots x 64 f32
  if (ki >= 2) {
#pragma unroll
    for (int qg = 0; qg < 2; ++qg) {
      const int s = (qi * 2 + qg) * 2 + (ki - 2);
#pragma unroll
      for (int vt = 0; vt < 2; ++vt)
#pragma unroll
        for (int r = 0; r < 16; ++r)
          Oc[s * 2048 + (vt * 16 + r) * 64 + lane] = oacc[qg][vt][r];
      Lc[s * 64 + lane] = lpart[qg];
    }
  }
  __syncthreads();
  if (ki < 2) {
#pragma unroll
    for (int qg = 0; qg < 2; ++qg) {
      const int s = (qi * 2 + qg) * 2 + ki;
#pragma unroll
      for (int vt = 0; vt < 2; ++vt)
#pragma unroll
        for (int r = 0; r < 16; ++r)
          oacc[qg][vt][r] += Oc[s * 2048 + (vt * 16 + r) * 64 + lane];
      lpart[qg] += Lc[s * 64 + lane];
    }
  }
  __syncthreads();  // WAR: round-A reads done before round-B rewrite
  if (ki == 1) {
#pragma unroll
    for (int qg = 0; qg < 2; ++qg) {
      const int s = (qi * 2 + qg) * 2;
#pragma unroll
      for (int vt = 0; vt < 2; ++vt)
#pragma unroll
        for (int r = 0; r < 16; ++r)
          Oc[s * 2048 + (vt * 16 + r) * 64 + lane] = oacc[qg][vt][r];
      Lc[s * 64 + lane] = lpart[qg];
    }
  }
  __syncthreads();
  if (ki == 0) {
#pragma unroll
    for (int qg = 0; qg < 2; ++qg) {
      const int s = (qi * 2 + qg) * 2;
#pragma unroll
      for (int vt = 0; vt < 2; ++vt)
#pragma unroll
        for (int r = 0; r < 16; ++r)
          oacc[qg][vt][r] += Oc[s * 2048 + (vt * 16 + r) * 64 + lane];
      float lp = lpart[qg] + Lc[s * 64 + lane];

      // lane-halves hold disjoint kv subsets of the same q
      lp += __shfl_xor(lp, 32);
      const float inv = 1.0f / lp;

      // O^T C-layout: q = ln, d = vt*32 + g*8 + hf*4 + j; Og row-major [s][E]
      bf16* orow =
          Og +
          ((size_t)b * S + (size_t)(blockIdx.x * 4 + qi * 2 + qg) * 32 + ln) *
              E +
          h * 64;
#pragma unroll
      for (int vt = 0; vt < 2; ++vt) {
#pragma unroll
        for (int g = 0; g < 4; ++g) {
          bf16x4 o;
#pragma unroll
          for (int j = 0; j < 4; ++j)
            o[j] = (bf16)(oacc[qg][vt][g * 4 + j] * inv);
          *(bf16x4*)&orow[vt * 32 + g * 8 + hf * 4] = o;
        }
      }
    }
  }
}

// ---------------------------------------------------------------------------
extern "C" void kernel_launch(void* const* d_in, const int* in_sizes, int n_in,
                              void* d_out, int out_size, void* d_ws, size_t ws_size,
                              hipStream_t stream) {
  const float* x = (const float*)d_in[0];
  const float* Wq = (const float*)d_in[1];
  const float* bq = (const float*)d_in[2];
  const float* Wk = (const float*)d_in[3];
  const float* bk = (const float*)d_in[4];
  const float* Wv = (const float*)d_in[5];
  const float* bv = (const float*)d_in[6];
  const float* Wo = (const float*)d_in[7];
  const float* bo = (const float*)d_in[8];

  const size_t ME = (size_t)4096 * 1024;  // 4M elems
  const size_t WE = (size_t)1024 * 1024;  // 1M elems
  bf16* xb = (bf16*)d_ws;
  bf16* wqt = xb + ME;
  bf16* wkt = wqt + WE;
  bf16* wvt = wkt + WE;
  bf16* wot = wvt + WE;
  bf16* qb = wot + WE;   // Q frags
  bf16* kb = qb + ME;    // K frags
  bf16* vt = kb + ME;    // V frags
  bf16* ab = vt + ME;    // attn out, row-major [B*S][E]

  cast_x<<<2048, 256, 0, stream>>>(x, xb);
  transpose_cast_w<<<dim3(16, 16, 4), 256, 0, stream>>>(Wq, Wk, Wv, Wo, wqt, wkt,
                                                        wvt, wot);
  gemm_qkv<<<dim3(8, 32, 3), 256, 0, stream>>>(xb, wqt, bq, bk, bv, qb, kb, vt);
  attn_mfma<<<dim3(S / 128, H, 2), 512, 0, stream>>>(qb, kb, vt, ab);
  gemm_wo<<<dim3(8, 64), 256, 0, stream>>>(ab, wot, bo, (float*)d_out);
}

// Round 8
// 200.691 us; speedup vs baseline: 1.5445x; 1.3423x over previous
//
#include <hip/hip_runtime.h>
#include <math.h>
#include <stdint.h>

typedef __bf16 bf16;
typedef __bf16 bf16x2 __attribute__((ext_vector_type(2)));
typedef __bf16 bf16x4 __attribute__((ext_vector_type(4)));
typedef __bf16 bf16x8 __attribute__((ext_vector_type(8)));
typedef float f32x4 __attribute__((ext_vector_type(4)));
typedef float f32x16 __attribute__((ext_vector_type(16)));

constexpr int E = 1024;   // embed dim
constexpr int S = 2048;   // seq len
constexpr int H = 16;     // heads (Dh = 64)

// Fragment layouts (1KB blocks, lane l = hf*32 + ln, 16B per lane):
//  Q/K frag: per (b,h): block (t, c), t = s/32 (64), c = d-chunk/16 (4).
//    lane l = hf*32 + (s%32); bytes = X[s][c*16 + hf*8 + j], j=0..7.
//    elem addr = (bh*256 + t*4 + c)*512 + l*8 + j        (131072 elems per bh)
//  V frag: per (b,h): block (tau, mt, c), tau = s/64 (32), mt = d/32 (2),
//    c = s-chunk-in-tile/16 (4). lane l = hf*32 + (d%32);
//    bytes = V^T[d][tau*64 + c*16 + hf*8 + j].
//    elem addr = (bh*256 + tau*8 + mt*4 + c)*512 + l*8 + j

// async global->LDS, 16B per lane; LDS dst = wave-uniform base + lane*16
__device__ __forceinline__ void gload16(const void* g, void* l) {
  __builtin_amdgcn_global_load_lds(
      (__attribute__((address_space(1))) void*)(uintptr_t)g,
      (__attribute__((address_space(3))) void*)(uint32_t)(uintptr_t)l, 16, 0, 0);
}

__device__ __forceinline__ f32x4 mfma16(bf16x8 a, bf16x8 b, f32x4 c) {
  return __builtin_amdgcn_mfma_f32_16x16x32_bf16(a, b, c, 0, 0, 0);
}
__device__ __forceinline__ f32x16 mfma32(bf16x8 a, bf16x8 b, f32x16 c) {
  return __builtin_amdgcn_mfma_f32_32x32x16_bf16(a, b, c, 0, 0, 0);
}

// native 2^x: ONE v_exp_f32 (NOT exp2f -> libm bloat, R1's regression)
__device__ __forceinline__ float fexp2(float x) {
#if __has_builtin(__builtin_amdgcn_exp2f)
  return __builtin_amdgcn_exp2f(x);
#else
  float r;
  asm("v_exp_f32 %0, %1" : "=v"(r) : "v"(x));
  return r;
#endif
}

// pack 2 f32 -> u32 of 2 bf16
__device__ __forceinline__ uint32_t pkbf(float lo, float hi) {
  bf16x2 p;
  p[0] = (bf16)lo;
  p[1] = (bf16)hi;
  return __builtin_bit_cast(uint32_t, p);
}

// ---------------------------------------------------------------------------
// cast x (fp32) -> bf16, 8 elems/thread
// ---------------------------------------------------------------------------
__global__ __launch_bounds__(256) void cast_x(const float* __restrict__ x,
                                              bf16* __restrict__ o) {
  const size_t i = ((size_t)blockIdx.x * 256 + threadIdx.x) * 8;
  const float4 a = *(const float4*)(x + i);
  const float4 b = *(const float4*)(x + i + 4);
  bf16x8 r;
  r[0] = (bf16)a.x; r[1] = (bf16)a.y; r[2] = (bf16)a.z; r[3] = (bf16)a.w;
  r[4] = (bf16)b.x; r[5] = (bf16)b.y; r[6] = (bf16)b.z; r[7] = (bf16)b.w;
  *(bf16x8*)(o + i) = r;
}

// ---------------------------------------------------------------------------
// W[k][n] fp32 -> Wt[n][k] bf16 (all 4 weight matrices, blockIdx.z selects)
// ---------------------------------------------------------------------------
__global__ __launch_bounds__(256) void transpose_cast_w(
    const float* __restrict__ W0, const float* __restrict__ W1,
    const float* __restrict__ W2, const float* __restrict__ W3,
    bf16* __restrict__ T0, bf16* __restrict__ T1, bf16* __restrict__ T2,
    bf16* __restrict__ T3) {
  const float* W;
  bf16* T;
  switch (blockIdx.z) {
    case 0: W = W0; T = T0; break;
    case 1: W = W1; T = T1; break;
    case 2: W = W2; T = T2; break;
    default: W = W3; T = T3; break;
  }
  __shared__ float t[64][65];
  const int k0 = blockIdx.y * 64, n0 = blockIdx.x * 64;
  const int tr = threadIdx.x >> 4;          // 0..15
  const int tc = (threadIdx.x & 15) * 4;    // 0..60
#pragma unroll
  for (int u = 0; u < 4; ++u) {
    const float4 v = *(const float4*)(W + (size_t)(k0 + tr + u * 16) * E + n0 + tc);
    t[tr + u * 16][tc + 0] = v.x;
    t[tr + u * 16][tc + 1] = v.y;
    t[tr + u * 16][tc + 2] = v.z;
    t[tr + u * 16][tc + 3] = v.w;
  }
  __syncthreads();
#pragma unroll
  for (int u = 0; u < 4; ++u) {
    const int n = tr + u * 16;
    bf16x4 o;
#pragma unroll
    for (int i = 0; i < 4; ++i) o[i] = (bf16)t[tc + i][n];
    *(bf16x4*)(T + (size_t)(n0 + n) * E + k0 + tc) = o;
  }
}

// ---------------------------------------------------------------------------
// Fused QKV GEMM, 256x256-tile 8-phase schedule (T2+T3+T4+T5).
// ONE GEMM: A = xb[4096][1024], B = Wt[3072][1024] (wqt/wkt/wvt contiguous);
// z = bx>>2 (1024%256==0 -> tiles never straddle z). Grid 12x16 = 192 blocks,
// 512 thr = 8 waves (2M x 4N), per-wave 128x64 out, BK=64, K=1024 -> 16
// K-tiles, 2 per outer iter.
// LDS 128KB: buf d at d*65536; A halves at +h*16384 (each [128][64] bf16
// row-major); B at +32768+h*16384.
// st_16x32 swizzle (rule #21, both-sides): linear LDS dest; SOURCE col
// pre-XOR'd by ((row>>2)&1)<<4 elems; ds_read byte XOR ((ln>>2)&1)<<5.
// Counted vmcnt (derived from the issue schedule below): vmcnt(4) at phase
// ends 3 and 7; tail iter drops prefetches -> vmcnt(0) at phase 3.
// Prefetch issue schedule (1 half-tile = 2 gloads/thread), slots freed by
// the preceding phase's barriers:
//   ph0: A(kt1)h0->buf1 | ph1: A(kt1)h1, B(kt0+2)h0->buf0 | ph2: B(kt0+2)h1
//   ph4: A(kt0+2)h0->buf0 | ph5: A(kt0+2)h1 | ph6: B(kt1+2)h0->buf1
//   ph7: B(kt1+2)h1
// Epilogue: frag-scatter identical to the proven per-z code (rt -> mf&3).
// ---------------------------------------------------------------------------
__global__ __launch_bounds__(512, 2) void gemm_qkv(const bf16* __restrict__ A,
                                                   const bf16* __restrict__ Wt,
                                                   const float* __restrict__ bq,
                                                   const float* __restrict__ bk,
                                                   const float* __restrict__ bv,
                                                   bf16* __restrict__ qo,
                                                   bf16* __restrict__ ko,
                                                   bf16* __restrict__ vo) {
  __shared__ __attribute__((aligned(16))) char smem[131072];
  const int tid = threadIdx.x;
  const int lane = tid & 63, quad = lane >> 4, ln = lane & 15;
  const int wid = tid >> 6, wr = wid >> 2, wc = wid & 3;

  // XCD swizzle (bijective: 192 = 8*24): each XCD gets 2 full m-panels.
  const int id = blockIdx.x + 12 * blockIdx.y;
  const int sw = (id & 7) * 24 + (id >> 3);
  const int bx = sw % 12, by = sw / 12;
  const int bm = by * 256, bn = bx * 256;
  const int z = bx >> 2;

  // staging geometry: thread covers rows r0, r0+64 of a half, col chunk c0;
  // source col pre-swizzled (involution keyed on row bit 2).
  const int r0 = tid >> 3;
  const int csw = ((tid & 7) * 8) ^ (((r0 >> 2) & 1) << 4);
  const bf16* Ag0 = A + (size_t)bm * E;
  const bf16* Bg0 = Wt + (size_t)bn * E;

#define STG(srcp, dd, boff, h, kt)                                            \
  do {                                                                        \
    const bf16* s_ = (srcp) + (size_t)((h) * 128 + r0) * E + (kt) * 64 + csw; \
    char* d_ = smem + (dd) * 65536 + (boff) + (h) * 16384 + tid * 16;         \
    gload16(s_, d_);                                                          \
    gload16(s_ + (size_t)64 * E, d_ + 8192);                                  \
  } while (0)

  // ds-read bases (swizzled read: XOR byte bit5 with ln bit2)
  const int sx = ((ln >> 2) & 1) << 5;
  const int lnq = ln * 128 + quad * 16;
  const int bB = (wc & 1) * 8192 + lnq;
  const char* Ab0 = smem + wr * 16384;
  const char* Bb0 = smem + 32768 + (wc >> 1) * 16384;

  f32x4 acc[8][4] = {};

  // prologue: A(0), B(0), B(1) = 12 loads/thread; allow B(1) in flight.
  STG(Ag0, 0, 0, 0, 0);
  STG(Ag0, 0, 0, 1, 0);
  STG(Bg0, 0, 32768, 0, 0);
  STG(Bg0, 0, 32768, 1, 0);
  STG(Bg0, 1, 32768, 0, 1);
  STG(Bg0, 1, 32768, 1, 1);
  asm volatile("s_waitcnt vmcnt(4)" ::: "memory");
  __builtin_amdgcn_s_barrier();

  for (int j = 0; j < 8; ++j) {
    const int kt0 = 2 * j, kt1 = 2 * j + 1;
    bf16x8 bfr[4][2];
#pragma unroll
    for (int p = 0; p < 8; ++p) {
      const int d = p >> 2, q = p & 3;
      const char* Ab = Ab0 + d * 65536;
      const char* Bb = Bb0 + d * 65536;

      // ds reads for this phase (B once per K-tile at q==0; A quadrant q)
      if (q == 0) {
#pragma unroll
        for (int nf = 0; nf < 4; ++nf)
#pragma unroll
          for (int ks = 0; ks < 2; ++ks)
            bfr[nf][ks] =
                *(const bf16x8*)(Bb + ((bB + nf * 2048 + ks * 64) ^ sx));
      }
      bf16x8 afr[2][2];
#pragma unroll
      for (int m2 = 0; m2 < 2; ++m2)
#pragma unroll
        for (int ks = 0; ks < 2; ++ks)
          afr[m2][ks] = *(const bf16x8*)(
              Ab + ((lnq + (q * 2 + m2) * 2048 + ks * 64) ^ sx));

      // prefetch issues (see schedule in header)
      if (p == 0) {
        STG(Ag0, 1, 0, 0, kt1);
      } else if (p == 1) {
        STG(Ag0, 1, 0, 1, kt1);
        if (kt0 + 2 < 16) STG(Bg0, 0, 32768, 0, kt0 + 2);
      } else if (p == 2) {
        if (kt0 + 2 < 16) STG(Bg0, 0, 32768, 1, kt0 + 2);
      } else if (p == 4) {
        if (kt0 + 2 < 16) STG(Ag0, 0, 0, 0, kt0 + 2);
      } else if (p == 5) {
        if (kt0 + 2 < 16) STG(Ag0, 0, 0, 1, kt0 + 2);
      } else if (p == 6) {
        if (kt1 + 2 < 16) STG(Bg0, 1, 32768, 0, kt1 + 2);
      } else if (p == 7) {
        if (kt1 + 2 < 16) STG(Bg0, 1, 32768, 1, kt1 + 2);
      }

      // counted vmcnt gates (derived; tail iter must fully drain)
      if (q == 3) {
        if (p == 3) {
          if (j < 7)
            asm volatile("s_waitcnt vmcnt(4)" ::: "memory");
          else
            asm volatile("s_waitcnt vmcnt(0)" ::: "memory");
        } else {  // p == 7
          if (j < 7) asm volatile("s_waitcnt vmcnt(4)" ::: "memory");
        }
      }

      __builtin_amdgcn_s_barrier();
      asm volatile("s_waitcnt lgkmcnt(0)" ::: "memory");
      __builtin_amdgcn_sched_barrier(0);  // rule #18: pin MFMA below the wait
      __builtin_amdgcn_s_setprio(1);
#pragma unroll
      for (int m2 = 0; m2 < 2; ++m2)
#pragma unroll
        for (int nf = 0; nf < 4; ++nf) {
          acc[q * 2 + m2][nf] = mfma16(afr[m2][0], bfr[nf][0], acc[q * 2 + m2][nf]);
          acc[q * 2 + m2][nf] = mfma16(afr[m2][1], bfr[nf][1], acc[q * 2 + m2][nf]);
        }
      __builtin_amdgcn_s_setprio(0);
      __builtin_amdgcn_s_barrier();
    }
  }
#undef STG

  // ---- epilogue: bias + scale + frag-layout scatter (proven formulas) ----
  const float* bias = (z == 0) ? bq : (z == 1) ? bk : bv;
  const float scl = (z == 0) ? 0.18033688f : 1.0f;  // 0.125*log2(e)
  const int hglob = (bx & 3) * 4 + wc;  // head (wave's 64-col span = 1 head)
  float bvv[4];
#pragma unroll
  for (int nf = 0; nf < 4; ++nf)
    bvv[nf] = bias[(bn + wc * 64 + nf * 16 + ln) & 1023];

#pragma unroll
  for (int mf = 0; mf < 8; ++mf) {
    const int row0 = bm + wr * 128 + mf * 16 + quad * 4;
    const int bb = row0 >> 11;   // batch (256-row tiles never span)
    const int rl = row0 & 2047;  // seq within batch
    const size_t hb = (size_t)(bb * 16 + hglob) * 131072;
#pragma unroll
    for (int nf = 0; nf < 4; ++nf) {
      if (z == 2) {
        // V frag: mt = nf>>1, ln32 = (nf&1)*16+ln; c-block = mf&3;
        // tau = rl>>6, hfv = (rl>>3)&1, j0 = rl&7
        const int mt = nf >> 1, ln32 = ((nf & 1) << 4) | ln;
        const int tau = rl >> 6, hfv = (rl >> 3) & 1, j0 = rl & 7;
        bf16x4 pp;
#pragma unroll
        for (int r = 0; r < 4; ++r) pp[r] = (bf16)(acc[mf][nf][r] + bvv[nf]);
        *(bf16x4*)&vo[hb + (size_t)((tau * 8 + mt * 4 + (mf & 3)) * 512 +
                                    hfv * 256 + ln32 * 8 + j0)] = pp;
      } else {
        bf16* o = (z == 0) ? qo : ko;
        const int t = rl >> 5, ln0 = rl & 31;
        const size_t base =
            hb + (size_t)((t * 4 + nf) * 512 + (ln >> 3) * 256 + (ln & 7));
#pragma unroll
        for (int r = 0; r < 4; ++r)
          o[base + (ln0 + r) * 8] = (bf16)((acc[mf][nf][r] + bvv[nf]) * scl);
      }
    }
  }
}

// ---------------------------------------------------------------------------
// Output GEMM: C[4096][1024] fp32 = A @ Wt^T + bias. 64x128 tile -> 512 blocks.
// ---------------------------------------------------------------------------
__global__ __launch_bounds__(256) void gemm_wo(const bf16* __restrict__ A,
                                               const bf16* __restrict__ Bt,
                                               const float* __restrict__ bias,
                                               float* __restrict__ C) {
  __shared__ __attribute__((aligned(16))) bf16 Asm[64 * 32];
  __shared__ __attribute__((aligned(16))) bf16 Bsm[128 * 32];
  const int tid = threadIdx.x;
  const int w = tid >> 6, lane = tid & 63, quad = lane >> 4, ln = lane & 15;
  const int bm = blockIdx.y * 64, bn = blockIdx.x * 128;
  const int wr = w >> 1, wc = w & 1;
  const int sr = lane >> 2, sc = (lane & 3) * 8;
  const bf16* Ag = A + (size_t)(bm + w * 16 + sr) * E + sc;
  const bf16* Bg = Bt + (size_t)(bn + w * 32 + sr) * E + sc;
  f32x4 acc[2][4] = {};

  for (int k0 = 0; k0 < E; k0 += 32) {
    gload16(Ag + k0, &Asm[(w * 16) * 32]);
    gload16(Bg + k0, &Bsm[(w * 32) * 32]);
    gload16(Bg + k0 + (size_t)16 * E, &Bsm[(w * 32 + 16) * 32]);
    __syncthreads();
    bf16x8 af[2], bfr[4];
#pragma unroll
    for (int t = 0; t < 2; ++t)
      af[t] = *(const bf16x8*)&Asm[(wr * 32 + t * 16 + ln) * 32 + quad * 8];
#pragma unroll
    for (int t = 0; t < 4; ++t)
      bfr[t] = *(const bf16x8*)&Bsm[(wc * 64 + t * 16 + ln) * 32 + quad * 8];
#pragma unroll
    for (int rt = 0; rt < 2; ++rt)
#pragma unroll
      for (int ct = 0; ct < 4; ++ct)
        acc[rt][ct] = mfma16(af[rt], bfr[ct], acc[rt][ct]);
    __syncthreads();
  }

  float bvv[4];
#pragma unroll
  for (int ct = 0; ct < 4; ++ct) bvv[ct] = bias[bn + wc * 64 + ct * 16 + ln];
#pragma unroll
  for (int rt = 0; rt < 2; ++rt) {
    const int row0 = bm + wr * 32 + rt * 16 + quad * 4;
#pragma unroll
    for (int ct = 0; ct < 4; ++ct) {
      const int c = bn + wc * 64 + ct * 16 + ln;
#pragma unroll
      for (int r = 0; r < 4; ++r)
        C[(size_t)(row0 + r) * E + c] = acc[rt][ct][r] + bvv[ct];
    }
  }
}

// ---------------------------------------------------------------------------
// MFMA flash attention v11 (R5, PROVEN 42.9us — structural optimum: 16
// waves/CU requires <=128 regs/wave which forces 1 q-group; R3/R6/R7 all
// regressed trying to leave this corner). Frozen.
// ---------------------------------------------------------------------------
__global__ __launch_bounds__(512, 4) void attn_mfma(const bf16* __restrict__ Qf,
                                                    const bf16* __restrict__ Kf,
                                                    const bf16* __restrict__ Vf,
                                                    bf16* __restrict__ Og) {
  // buffer b at smem + b*32768: [K: 2 ki x 4096 elems][V: 2 ki x 4096 elems]
  __shared__ __attribute__((aligned(16))) char smem[65536];

  const int tid = threadIdx.x;
  const int w = tid >> 6, lane = tid & 63, ln = lane & 31, hf = lane >> 5;
  const int qi = w & 3, ki = w >> 2;
  const int tq = blockIdx.x * 4 + qi;       // q-tile (32 q-rows)
  const int h = blockIdx.y, b = blockIdx.z;
  const size_t fb = (size_t)(b * H + h) * 131072;

  // Q B-frags once (B[k=d][n=q]): lane q = ln, d = c*16 + hf*8 + j
  bf16x8 qf[4];
  {
    const bf16* qb = Qf + fb + (size_t)tq * 2048 + lane * 8;
#pragma unroll
    for (int c = 0; c < 4; ++c) qf[c] = *(const bf16x8*)(qb + c * 512);
  }

  // staging: wave (qi,ki) copies chunks qi*2, qi*2+1 of its group's tile
  const bf16* Ksrc = Kf + fb + qi * 1024 + lane * 8;
  const bf16* Vsrc = Vf + fb + qi * 1024 + lane * 8;
  const int dstoff = ki * 4096 + qi * 1024;  // elems within a buffer's K or V

  float lpart = 0.f;
  f32x16 oacc[2] = {};

#define STAGE(i, buf)                                                  \
  do {                                                                 \
    const size_t toff = (size_t)(ki * 16 + (i)) * 4096;                \
    bf16* kd = (bf16*)(smem + (buf) * 32768) + dstoff;                 \
    bf16* vd = (bf16*)(smem + (buf) * 32768 + 16384) + dstoff;         \
    gload16(Ksrc + toff, kd);                                          \
    gload16(Ksrc + toff + 512, kd + 512);                              \
    gload16(Vsrc + toff, vd);                                          \
    gload16(Vsrc + toff + 512, vd + 512);                              \
  } while (0)

  STAGE(0, 0);
  __syncthreads();  // vmcnt(0)+barrier: tile 0 staged

#pragma unroll 2
  for (int i = 0; i < 16; ++i) {
    const int cur = i & 1;
    if (i < 15) STAGE(i + 1, cur ^ 1);  // prefetch: latency hides under MFMA
    const bf16* Ks = (const bf16*)(smem + cur * 32768) + ki * 4096;
    const bf16* Vs = (const bf16*)(smem + cur * 32768 + 16384) + ki * 4096;

#pragma unroll
    for (int mt = 0; mt < 2; ++mt) {
      // scores S^T (rows kv, cols q): A = K frags, B = qf
      f32x16 st = {};
      __builtin_amdgcn_s_setprio(1);
#pragma unroll
      for (int c = 0; c < 4; ++c)
        st = mfma32(*(const bf16x8*)&Ks[(mt * 4 + c) * 512 + lane * 8], qf[c],
                    st);
      __builtin_amdgcn_s_setprio(0);

      // P = 2^st (Q carries 0.125*log2e); C-layout kv = 8g + 4hf + j
      float pe[16];
#pragma unroll
      for (int r = 0; r < 16; ++r) pe[r] = fexp2(st[r]);
      // tree-reduce row-sum (short dep chain, not a 16-long serial fadd)
      lpart += (((pe[0] + pe[1]) + (pe[2] + pe[3])) +
                ((pe[4] + pe[5]) + (pe[6] + pe[7]))) +
               (((pe[8] + pe[9]) + (pe[10] + pe[11])) +
                ((pe[12] + pe[13]) + (pe[14] + pe[15])));

      // Build PV B-frags in-register (T12): one permlane32_swap fills two
      // words: swap(pk(g0:j0,j1), pk(g1:j0,j1)) -> word0 (j0,j1), word2.
      bf16x8 pb[2];
#pragma unroll
      for (int cl = 0; cl < 2; ++cl) {
        uint32_t a01 = pkbf(pe[cl * 8 + 0], pe[cl * 8 + 1]);
        uint32_t a23 = pkbf(pe[cl * 8 + 2], pe[cl * 8 + 3]);
        uint32_t b01 = pkbf(pe[cl * 8 + 4], pe[cl * 8 + 5]);
        uint32_t b23 = pkbf(pe[cl * 8 + 6], pe[cl * 8 + 7]);
        auto r0 = __builtin_amdgcn_permlane32_swap(a01, b01, false, false);
        auto r1 = __builtin_amdgcn_permlane32_swap(a23, b23, false, false);
        union {
          bf16x8 v;
          uint32_t u[4];
        } pu;
        pu.u[0] = r0[0];
        pu.u[1] = r1[0];
        pu.u[2] = r0[1];
        pu.u[3] = r1[1];
        pb[cl] = pu.v;
      }

      // O^T += V^T . P^T  (A = V frags, kv-chunk c = mt*2 + cl)
      __builtin_amdgcn_s_setprio(1);
#pragma unroll
      for (int vt = 0; vt < 2; ++vt) {
        oacc[vt] = mfma32(
            *(const bf16x8*)&Vs[(vt * 4 + mt * 2 + 0) * 512 + lane * 8], pb[0],
            oacc[vt]);
        oacc[vt] = mfma32(
            *(const bf16x8*)&Vs[(vt * 4 + mt * 2 + 1) * 512 + lane * 8], pb[1],
            oacc[vt]);
      }
      __builtin_amdgcn_s_setprio(0);
    }
    __syncthreads();  // reads retired + next tile's gloads drained (vmcnt 0)
  }
#undef STAGE

  // ---- kv-half combine (deferred softmax => partials just add) ----
  float* Ocmb = (float*)smem;            // 4 qi x 32 x 64 f32 = 32 KB
  float* Lcmb = (float*)(smem + 32768);  // 4 qi x 64 f32
  if (ki == 1) {
#pragma unroll
    for (int vt = 0; vt < 2; ++vt)
#pragma unroll
      for (int r = 0; r < 16; ++r)
        Ocmb[qi * 2048 + (vt * 16 + r) * 64 + lane] = oacc[vt][r];
    Lcmb[qi * 64 + lane] = lpart;
  }
  __syncthreads();
  if (ki == 0) {
#pragma unroll
    for (int vt = 0; vt < 2; ++vt)
#pragma unroll
      for (int r = 0; r < 16; ++r)
        oacc[vt][r] += Ocmb[qi * 2048 + (vt * 16 + r) * 64 + lane];
    lpart += Lcmb[qi * 64 + lane];

    // lane-halves hold disjoint kv subsets of the same q
    lpart += __shfl_xor(lpart, 32);
    const float inv = 1.0f / lpart;

    // O^T C-layout: q = ln, d = vt*32 + g*8 + hf*4 + j; Og row-major [s][E]
    bf16* orow = Og + ((size_t)b * S + (size_t)tq * 32 + ln) * E + h * 64;
#pragma unroll
    for (int vt = 0; vt < 2; ++vt) {
#pragma unroll
      for (int g = 0; g < 4; ++g) {
        bf16x4 o;
#pragma unroll
        for (int j = 0; j < 4; ++j) o[j] = (bf16)(oacc[vt][g * 4 + j] * inv);
        *(bf16x4*)&orow[vt * 32 + g * 8 + hf * 4] = o;
      }
    }
  }
}

// ---------------------------------------------------------------------------
extern "C" void kernel_launch(void* const* d_in, const int* in_sizes, int n_in,
                              void* d_out, int out_size, void* d_ws, size_t ws_size,
                              hipStream_t stream) {
  const float* x = (const float*)d_in[0];
  const float* Wq = (const float*)d_in[1];
  const float* bq = (const float*)d_in[2];
  const float* Wk = (const float*)d_in[3];
  const float* bk = (const float*)d_in[4];
  const float* Wv = (const float*)d_in[5];
  const float* bv = (const float*)d_in[6];
  const float* Wo = (const float*)d_in[7];
  const float* bo = (const float*)d_in[8];

  const size_t ME = (size_t)4096 * 1024;  // 4M elems
  const size_t WE = (size_t)1024 * 1024;  // 1M elems
  bf16* xb = (bf16*)d_ws;
  bf16* wqt = xb + ME;
  bf16* wkt = wqt + WE;   // contiguous with wqt: fused B = [3072][1024]
  bf16* wvt = wkt + WE;
  bf16* wot = wvt + WE;
  bf16* qb = wot + WE;   // Q frags
  bf16* kb = qb + ME;    // K frags
  bf16* vt = kb + ME;    // V frags
  bf16* ab = vt + ME;    // attn out, row-major [B*S][E]

  cast_x<<<2048, 256, 0, stream>>>(x, xb);
  transpose_cast_w<<<dim3(16, 16, 4), 256, 0, stream>>>(Wq, Wk, Wv, Wo, wqt, wkt,
                                                        wvt, wot);
  gemm_qkv<<<dim3(12, 16), 512, 0, stream>>>(xb, wqt, bq, bk, bv, qb, kb, vt);
  attn_mfma<<<dim3(S / 128, H, 2), 512, 0, stream>>>(qb, kb, vt, ab);
  gemm_wo<<<dim3(8, 64), 256, 0, stream>>>(ab, wot, bo, (float*)d_out);
}

// Round 9
// 194.590 us; speedup vs baseline: 1.5929x; 1.0314x over previous
//
#include <hip/hip_runtime.h>
#include <math.h>
#include <stdint.h>

typedef __bf16 bf16;
typedef __bf16 bf16x2 __attribute__((ext_vector_type(2)));
typedef __bf16 bf16x4 __attribute__((ext_vector_type(4)));
typedef __bf16 bf16x8 __attribute__((ext_vector_type(8)));
typedef float f32x4 __attribute__((ext_vector_type(4)));
typedef float f32x16 __attribute__((ext_vector_type(16)));

constexpr int E = 1024;   // embed dim
constexpr int S = 2048;   // seq len
constexpr int H = 16;     // heads (Dh = 64)

// Fragment layouts (1KB blocks, lane l = hf*32 + ln, 16B per lane):
//  Q/K frag: per (b,h): block (t, c), t = s/32 (64), c = d-chunk/16 (4).
//    lane l = hf*32 + (s%32); bytes = X[s][c*16 + hf*8 + j], j=0..7.
//    elem addr = (bh*256 + t*4 + c)*512 + l*8 + j        (131072 elems per bh)
//  V frag: per (b,h): block (tau, mt, c), tau = s/64 (32), mt = d/32 (2),
//    c = s-chunk-in-tile/16 (4). lane l = hf*32 + (d%32);
//    bytes = V^T[d][tau*64 + c*16 + hf*8 + j].
//    elem addr = (bh*256 + tau*8 + mt*4 + c)*512 + l*8 + j

// async global->LDS, 16B per lane; LDS dst = wave-uniform base + lane*16
__device__ __forceinline__ void gload16(const void* g, void* l) {
  __builtin_amdgcn_global_load_lds(
      (__attribute__((address_space(1))) void*)(uintptr_t)g,
      (__attribute__((address_space(3))) void*)(uint32_t)(uintptr_t)l, 16, 0, 0);
}

__device__ __forceinline__ f32x4 mfma16(bf16x8 a, bf16x8 b, f32x4 c) {
  return __builtin_amdgcn_mfma_f32_16x16x32_bf16(a, b, c, 0, 0, 0);
}
__device__ __forceinline__ f32x16 mfma32(bf16x8 a, bf16x8 b, f32x16 c) {
  return __builtin_amdgcn_mfma_f32_32x32x16_bf16(a, b, c, 0, 0, 0);
}

// native 2^x: ONE v_exp_f32 (NOT exp2f -> libm bloat, R1's regression)
__device__ __forceinline__ float fexp2(float x) {
#if __has_builtin(__builtin_amdgcn_exp2f)
  return __builtin_amdgcn_exp2f(x);
#else
  float r;
  asm("v_exp_f32 %0, %1" : "=v"(r) : "v"(x));
  return r;
#endif
}

// pack 2 f32 -> u32 of 2 bf16
__device__ __forceinline__ uint32_t pkbf(float lo, float hi) {
  bf16x2 p;
  p[0] = (bf16)lo;
  p[1] = (bf16)hi;
  return __builtin_bit_cast(uint32_t, p);
}

// ---------------------------------------------------------------------------
// cast x (fp32) -> bf16, 8 elems/thread
// ---------------------------------------------------------------------------
__global__ __launch_bounds__(256) void cast_x(const float* __restrict__ x,
                                              bf16* __restrict__ o) {
  const size_t i = ((size_t)blockIdx.x * 256 + threadIdx.x) * 8;
  const float4 a = *(const float4*)(x + i);
  const float4 b = *(const float4*)(x + i + 4);
  bf16x8 r;
  r[0] = (bf16)a.x; r[1] = (bf16)a.y; r[2] = (bf16)a.z; r[3] = (bf16)a.w;
  r[4] = (bf16)b.x; r[5] = (bf16)b.y; r[6] = (bf16)b.z; r[7] = (bf16)b.w;
  *(bf16x8*)(o + i) = r;
}

// ---------------------------------------------------------------------------
// W[k][n] fp32 -> Wt[n][k] bf16 (all 4 weight matrices, blockIdx.z selects)
// ---------------------------------------------------------------------------
__global__ __launch_bounds__(256) void transpose_cast_w(
    const float* __restrict__ W0, const float* __restrict__ W1,
    const float* __restrict__ W2, const float* __restrict__ W3,
    bf16* __restrict__ T0, bf16* __restrict__ T1, bf16* __restrict__ T2,
    bf16* __restrict__ T3) {
  const float* W;
  bf16* T;
  switch (blockIdx.z) {
    case 0: W = W0; T = T0; break;
    case 1: W = W1; T = T1; break;
    case 2: W = W2; T = T2; break;
    default: W = W3; T = T3; break;
  }
  __shared__ float t[64][65];
  const int k0 = blockIdx.y * 64, n0 = blockIdx.x * 64;
  const int tr = threadIdx.x >> 4;          // 0..15
  const int tc = (threadIdx.x & 15) * 4;    // 0..60
#pragma unroll
  for (int u = 0; u < 4; ++u) {
    const float4 v = *(const float4*)(W + (size_t)(k0 + tr + u * 16) * E + n0 + tc);
    t[tr + u * 16][tc + 0] = v.x;
    t[tr + u * 16][tc + 1] = v.y;
    t[tr + u * 16][tc + 2] = v.z;
    t[tr + u * 16][tc + 3] = v.w;
  }
  __syncthreads();
#pragma unroll
  for (int u = 0; u < 4; ++u) {
    const int n = tr + u * 16;
    bf16x4 o;
#pragma unroll
    for (int i = 0; i < 4; ++i) o[i] = (bf16)t[tc + i][n];
    *(bf16x4*)(T + (size_t)(n0 + n) * E + k0 + tc) = o;
  }
}

// ---------------------------------------------------------------------------
// Fused QKV GEMM, 256x256-tile 8-phase schedule (T2+T3+T4+T5).
// ONE GEMM: A = xb[4096][1024], B = Wt[3072][1024] (wqt/wkt/wvt contiguous);
// z = bx>>2 (1024%256==0 -> tiles never straddle z). Grid 12x16 = 192 blocks,
// 512 thr = 8 waves (2M x 4N), per-wave 128x64 out, BK=64, K=1024 -> 16
// K-tiles, 2 per outer iter.
// LDS 128KB: buf d at d*65536; A halves at +h*16384 (each [128][64] bf16
// row-major); B at +32768+h*16384.
// Swizzle (rule #21, both sides; R8 post-mortem): within each 128B row,
// 16B-granule index c (0..7) is XOR'd with (row&7) — 3-bit key so the 8
// lanes of each bank-phase octet (same granule, 8 different rows) spread
// over all 8 granules = conflict-free. R8's 1-bit key left 2.36M conflicts.
// LDS dest stays linear; SOURCE col pre-XOR'd; ds_read addr XOR'd.
// Counted vmcnt: vmcnt(4) at phase ends 3 and 7; tail iter vmcnt(0) at 3.
// Prefetch issue schedule (1 half-tile = 2 gloads/thread):
//   ph0: A(kt1)h0->buf1 | ph1: A(kt1)h1, B(kt0+2)h0->buf0 | ph2: B(kt0+2)h1
//   ph4: A(kt0+2)h0->buf0 | ph5: A(kt0+2)h1 | ph6: B(kt1+2)h0->buf1
//   ph7: B(kt1+2)h1
// ---------------------------------------------------------------------------
__global__ __launch_bounds__(512, 2) void gemm_qkv(const bf16* __restrict__ A,
                                                   const bf16* __restrict__ Wt,
                                                   const float* __restrict__ bq,
                                                   const float* __restrict__ bk,
                                                   const float* __restrict__ bv,
                                                   bf16* __restrict__ qo,
                                                   bf16* __restrict__ ko,
                                                   bf16* __restrict__ vo) {
  __shared__ __attribute__((aligned(16))) char smem[131072];
  const int tid = threadIdx.x;
  const int lane = tid & 63, quad = lane >> 4, ln = lane & 15;
  const int wid = tid >> 6, wr = wid >> 2, wc = wid & 3;

  // XCD swizzle (bijective: 192 = 8*24): each XCD gets 2 full m-panels.
  const int id = blockIdx.x + 12 * blockIdx.y;
  const int sw = (id & 7) * 24 + (id >> 3);
  const int bx = sw % 12, by = sw / 12;
  const int bm = by * 256, bn = bx * 256;
  const int z = bx >> 2;

  // staging: thread covers rows r0, r0+64 of a half, 16B col chunk tid&7;
  // source chunk pre-XOR'd with (row&7)  (3-bit involution key).
  const int r0 = tid >> 3;
  const int csw = ((tid & 7) * 8) ^ ((r0 & 7) * 8);
  const bf16* Ag0 = A + (size_t)bm * E;
  const bf16* Bg0 = Wt + (size_t)bn * E;

#define STG(srcp, dd, boff, h, kt)                                            \
  do {                                                                        \
    const bf16* s_ = (srcp) + (size_t)((h) * 128 + r0) * E + (kt) * 64 + csw; \
    char* d_ = smem + (dd) * 65536 + (boff) + (h) * 16384 + tid * 16;         \
    gload16(s_, d_);                                                          \
    gload16(s_ + (size_t)64 * E, d_ + 8192);                                  \
  } while (0)

  // ds-read: XOR granule with (row&7) = (ln&7) -> byte XOR (ln&7)<<4
  const int sx = (ln & 7) << 4;
  const int lnq = ln * 128 + quad * 16;
  const int bB = (wc & 1) * 8192 + lnq;
  const char* Ab0 = smem + wr * 16384;
  const char* Bb0 = smem + 32768 + (wc >> 1) * 16384;

  f32x4 acc[8][4] = {};

  // prologue: A(0), B(0), B(1) = 12 loads/thread; allow B(1) in flight.
  STG(Ag0, 0, 0, 0, 0);
  STG(Ag0, 0, 0, 1, 0);
  STG(Bg0, 0, 32768, 0, 0);
  STG(Bg0, 0, 32768, 1, 0);
  STG(Bg0, 1, 32768, 0, 1);
  STG(Bg0, 1, 32768, 1, 1);
  asm volatile("s_waitcnt vmcnt(4)" ::: "memory");
  __builtin_amdgcn_s_barrier();

  for (int j = 0; j < 8; ++j) {
    const int kt0 = 2 * j, kt1 = 2 * j + 1;
    bf16x8 bfr[4][2];
#pragma unroll
    for (int p = 0; p < 8; ++p) {
      const int d = p >> 2, q = p & 3;
      const char* Ab = Ab0 + d * 65536;
      const char* Bb = Bb0 + d * 65536;

      // ds reads for this phase (B once per K-tile at q==0; A quadrant q)
      if (q == 0) {
#pragma unroll
        for (int nf = 0; nf < 4; ++nf)
#pragma unroll
          for (int ks = 0; ks < 2; ++ks)
            bfr[nf][ks] =
                *(const bf16x8*)(Bb + ((bB + nf * 2048 + ks * 64) ^ sx));
      }
      bf16x8 afr[2][2];
#pragma unroll
      for (int m2 = 0; m2 < 2; ++m2)
#pragma unroll
        for (int ks = 0; ks < 2; ++ks)
          afr[m2][ks] = *(const bf16x8*)(
              Ab + ((lnq + (q * 2 + m2) * 2048 + ks * 64) ^ sx));

      // prefetch issues (see schedule in header)
      if (p == 0) {
        STG(Ag0, 1, 0, 0, kt1);
      } else if (p == 1) {
        STG(Ag0, 1, 0, 1, kt1);
        if (kt0 + 2 < 16) STG(Bg0, 0, 32768, 0, kt0 + 2);
      } else if (p == 2) {
        if (kt0 + 2 < 16) STG(Bg0, 0, 32768, 1, kt0 + 2);
      } else if (p == 4) {
        if (kt0 + 2 < 16) STG(Ag0, 0, 0, 0, kt0 + 2);
      } else if (p == 5) {
        if (kt0 + 2 < 16) STG(Ag0, 0, 0, 1, kt0 + 2);
      } else if (p == 6) {
        if (kt1 + 2 < 16) STG(Bg0, 1, 32768, 0, kt1 + 2);
      } else if (p == 7) {
        if (kt1 + 2 < 16) STG(Bg0, 1, 32768, 1, kt1 + 2);
      }

      // counted vmcnt gates (derived; tail iter must fully drain)
      if (q == 3) {
        if (p == 3) {
          if (j < 7)
            asm volatile("s_waitcnt vmcnt(4)" ::: "memory");
          else
            asm volatile("s_waitcnt vmcnt(0)" ::: "memory");
        } else {  // p == 7
          if (j < 7) asm volatile("s_waitcnt vmcnt(4)" ::: "memory");
        }
      }

      __builtin_amdgcn_s_barrier();
      asm volatile("s_waitcnt lgkmcnt(0)" ::: "memory");
      __builtin_amdgcn_sched_barrier(0);  // rule #18: pin MFMA below the wait
      __builtin_amdgcn_s_setprio(1);
#pragma unroll
      for (int m2 = 0; m2 < 2; ++m2)
#pragma unroll
        for (int nf = 0; nf < 4; ++nf) {
          acc[q * 2 + m2][nf] = mfma16(afr[m2][0], bfr[nf][0], acc[q * 2 + m2][nf]);
          acc[q * 2 + m2][nf] = mfma16(afr[m2][1], bfr[nf][1], acc[q * 2 + m2][nf]);
        }
      __builtin_amdgcn_s_setprio(0);
      __builtin_amdgcn_s_barrier();
    }
  }
#undef STG

  // ---- epilogue: bias + scale + frag-layout scatter (proven formulas) ----
  const float* bias = (z == 0) ? bq : (z == 1) ? bk : bv;
  const float scl = (z == 0) ? 0.18033688f : 1.0f;  // 0.125*log2(e)
  const int hglob = (bx & 3) * 4 + wc;  // head (wave's 64-col span = 1 head)
  float bvv[4];
#pragma unroll
  for (int nf = 0; nf < 4; ++nf)
    bvv[nf] = bias[(bn + wc * 64 + nf * 16 + ln) & 1023];

#pragma unroll
  for (int mf = 0; mf < 8; ++mf) {
    const int row0 = bm + wr * 128 + mf * 16 + quad * 4;
    const int bb = row0 >> 11;   // batch (256-row tiles never span)
    const int rl = row0 & 2047;  // seq within batch
    const size_t hb = (size_t)(bb * 16 + hglob) * 131072;
#pragma unroll
    for (int nf = 0; nf < 4; ++nf) {
      if (z == 2) {
        // V frag: mt = nf>>1, ln32 = (nf&1)*16+ln; c-block = mf&3;
        // tau = rl>>6, hfv = (rl>>3)&1, j0 = rl&7
        const int mt = nf >> 1, ln32 = ((nf & 1) << 4) | ln;
        const int tau = rl >> 6, hfv = (rl >> 3) & 1, j0 = rl & 7;
        bf16x4 pp;
#pragma unroll
        for (int r = 0; r < 4; ++r) pp[r] = (bf16)(acc[mf][nf][r] + bvv[nf]);
        *(bf16x4*)&vo[hb + (size_t)((tau * 8 + mt * 4 + (mf & 3)) * 512 +
                                    hfv * 256 + ln32 * 8 + j0)] = pp;
      } else {
        bf16* o = (z == 0) ? qo : ko;
        const int t = rl >> 5, ln0 = rl & 31;
        const size_t base =
            hb + (size_t)((t * 4 + nf) * 512 + (ln >> 3) * 256 + (ln & 7));
#pragma unroll
        for (int r = 0; r < 4; ++r)
          o[base + (ln0 + r) * 8] = (bf16)((acc[mf][nf][r] + bvv[nf]) * scl);
      }
    }
  }
}

// ---------------------------------------------------------------------------
// Output GEMM: C[4096][1024] fp32 = A @ Wt^T + bias. 64x128 tile -> 512 blocks.
// ---------------------------------------------------------------------------
__global__ __launch_bounds__(256) void gemm_wo(const bf16* __restrict__ A,
                                               const bf16* __restrict__ Bt,
                                               const float* __restrict__ bias,
                                               float* __restrict__ C) {
  __shared__ __attribute__((aligned(16))) bf16 Asm[64 * 32];
  __shared__ __attribute__((aligned(16))) bf16 Bsm[128 * 32];
  const int tid = threadIdx.x;
  const int w = tid >> 6, lane = tid & 63, quad = lane >> 4, ln = lane & 15;
  const int bm = blockIdx.y * 64, bn = blockIdx.x * 128;
  const int wr = w >> 1, wc = w & 1;
  const int sr = lane >> 2, sc = (lane & 3) * 8;
  const bf16* Ag = A + (size_t)(bm + w * 16 + sr) * E + sc;
  const bf16* Bg = Bt + (size_t)(bn + w * 32 + sr) * E + sc;
  f32x4 acc[2][4] = {};

  for (int k0 = 0; k0 < E; k0 += 32) {
    gload16(Ag + k0, &Asm[(w * 16) * 32]);
    gload16(Bg + k0, &Bsm[(w * 32) * 32]);
    gload16(Bg + k0 + (size_t)16 * E, &Bsm[(w * 32 + 16) * 32]);
    __syncthreads();
    bf16x8 af[2], bfr[4];
#pragma unroll
    for (int t = 0; t < 2; ++t)
      af[t] = *(const bf16x8*)&Asm[(wr * 32 + t * 16 + ln) * 32 + quad * 8];
#pragma unroll
    for (int t = 0; t < 4; ++t)
      bfr[t] = *(const bf16x8*)&Bsm[(wc * 64 + t * 16 + ln) * 32 + quad * 8];
#pragma unroll
    for (int rt = 0; rt < 2; ++rt)
#pragma unroll
      for (int ct = 0; ct < 4; ++ct)
        acc[rt][ct] = mfma16(af[rt], bfr[ct], acc[rt][ct]);
    __syncthreads();
  }

  float bvv[4];
#pragma unroll
  for (int ct = 0; ct < 4; ++ct) bvv[ct] = bias[bn + wc * 64 + ct * 16 + ln];
#pragma unroll
  for (int rt = 0; rt < 2; ++rt) {
    const int row0 = bm + wr * 32 + rt * 16 + quad * 4;
#pragma unroll
    for (int ct = 0; ct < 4; ++ct) {
      const int c = bn + wc * 64 + ct * 16 + ln;
#pragma unroll
      for (int r = 0; r < 4; ++r)
        C[(size_t)(row0 + r) * E + c] = acc[rt][ct][r] + bvv[ct];
    }
  }
}

// ---------------------------------------------------------------------------
// MFMA flash attention v11 (R5, PROVEN 42.9us — structural optimum: 16
// waves/CU requires <=128 regs/wave which forces 1 q-group; R3/R6/R7 all
// regressed trying to leave this corner). Frozen.
// ---------------------------------------------------------------------------
__global__ __launch_bounds__(512, 4) void attn_mfma(const bf16* __restrict__ Qf,
                                                    const bf16* __restrict__ Kf,
                                                    const bf16* __restrict__ Vf,
                                                    bf16* __restrict__ Og) {
  // buffer b at smem + b*32768: [K: 2 ki x 4096 elems][V: 2 ki x 4096 elems]
  __shared__ __attribute__((aligned(16))) char smem[65536];

  const int tid = threadIdx.x;
  const int w = tid >> 6, lane = tid & 63, ln = lane & 31, hf = lane >> 5;
  const int qi = w & 3, ki = w >> 2;
  const int tq = blockIdx.x * 4 + qi;       // q-tile (32 q-rows)
  const int h = blockIdx.y, b = blockIdx.z;
  const size_t fb = (size_t)(b * H + h) * 131072;

  // Q B-frags once (B[k=d][n=q]): lane q = ln, d = c*16 + hf*8 + j
  bf16x8 qf[4];
  {
    const bf16* qb = Qf + fb + (size_t)tq * 2048 + lane * 8;
#pragma unroll
    for (int c = 0; c < 4; ++c) qf[c] = *(const bf16x8*)(qb + c * 512);
  }

  // staging: wave (qi,ki) copies chunks qi*2, qi*2+1 of its group's tile
  const bf16* Ksrc = Kf + fb + qi * 1024 + lane * 8;
  const bf16* Vsrc = Vf + fb + qi * 1024 + lane * 8;
  const int dstoff = ki * 4096 + qi * 1024;  // elems within a buffer's K or V

  float lpart = 0.f;
  f32x16 oacc[2] = {};

#define STAGE(i, buf)                                                  \
  do {                                                                 \
    const size_t toff = (size_t)(ki * 16 + (i)) * 4096;                \
    bf16* kd = (bf16*)(smem + (buf) * 32768) + dstoff;                 \
    bf16* vd = (bf16*)(smem + (buf) * 32768 + 16384) + dstoff;         \
    gload16(Ksrc + toff, kd);                                          \
    gload16(Ksrc + toff + 512, kd + 512);                              \
    gload16(Vsrc + toff, vd);                                          \
    gload16(Vsrc + toff + 512, vd + 512);                              \
  } while (0)

  STAGE(0, 0);
  __syncthreads();  // vmcnt(0)+barrier: tile 0 staged

#pragma unroll 2
  for (int i = 0; i < 16; ++i) {
    const int cur = i & 1;
    if (i < 15) STAGE(i + 1, cur ^ 1);  // prefetch: latency hides under MFMA
    const bf16* Ks = (const bf16*)(smem + cur * 32768) + ki * 4096;
    const bf16* Vs = (const bf16*)(smem + cur * 32768 + 16384) + ki * 4096;

#pragma unroll
    for (int mt = 0; mt < 2; ++mt) {
      // scores S^T (rows kv, cols q): A = K frags, B = qf
      f32x16 st = {};
      __builtin_amdgcn_s_setprio(1);
#pragma unroll
      for (int c = 0; c < 4; ++c)
        st = mfma32(*(const bf16x8*)&Ks[(mt * 4 + c) * 512 + lane * 8], qf[c],
                    st);
      __builtin_amdgcn_s_setprio(0);

      // P = 2^st (Q carries 0.125*log2e); C-layout kv = 8g + 4hf + j
      float pe[16];
#pragma unroll
      for (int r = 0; r < 16; ++r) pe[r] = fexp2(st[r]);
      // tree-reduce row-sum (short dep chain, not a 16-long serial fadd)
      lpart += (((pe[0] + pe[1]) + (pe[2] + pe[3])) +
                ((pe[4] + pe[5]) + (pe[6] + pe[7]))) +
               (((pe[8] + pe[9]) + (pe[10] + pe[11])) +
                ((pe[12] + pe[13]) + (pe[14] + pe[15])));

      // Build PV B-frags in-register (T12): one permlane32_swap fills two
      // words: swap(pk(g0:j0,j1), pk(g1:j0,j1)) -> word0 (j0,j1), word2.
      bf16x8 pb[2];
#pragma unroll
      for (int cl = 0; cl < 2; ++cl) {
        uint32_t a01 = pkbf(pe[cl * 8 + 0], pe[cl * 8 + 1]);
        uint32_t a23 = pkbf(pe[cl * 8 + 2], pe[cl * 8 + 3]);
        uint32_t b01 = pkbf(pe[cl * 8 + 4], pe[cl * 8 + 5]);
        uint32_t b23 = pkbf(pe[cl * 8 + 6], pe[cl * 8 + 7]);
        auto r0 = __builtin_amdgcn_permlane32_swap(a01, b01, false, false);
        auto r1 = __builtin_amdgcn_permlane32_swap(a23, b23, false, false);
        union {
          bf16x8 v;
          uint32_t u[4];
        } pu;
        pu.u[0] = r0[0];
        pu.u[1] = r1[0];
        pu.u[2] = r0[1];
        pu.u[3] = r1[1];
        pb[cl] = pu.v;
      }

      // O^T += V^T . P^T  (A = V frags, kv-chunk c = mt*2 + cl)
      __builtin_amdgcn_s_setprio(1);
#pragma unroll
      for (int vt = 0; vt < 2; ++vt) {
        oacc[vt] = mfma32(
            *(const bf16x8*)&Vs[(vt * 4 + mt * 2 + 0) * 512 + lane * 8], pb[0],
            oacc[vt]);
        oacc[vt] = mfma32(
            *(const bf16x8*)&Vs[(vt * 4 + mt * 2 + 1) * 512 + lane * 8], pb[1],
            oacc[vt]);
      }
      __builtin_amdgcn_s_setprio(0);
    }
    __syncthreads();  // reads retired + next tile's gloads drained (vmcnt 0)
  }
#undef STAGE

  // ---- kv-half combine (deferred softmax => partials just add) ----
  float* Ocmb = (float*)smem;            // 4 qi x 32 x 64 f32 = 32 KB
  float* Lcmb = (float*)(smem + 32768);  // 4 qi x 64 f32
  if (ki == 1) {
#pragma unroll
    for (int vt = 0; vt < 2; ++vt)
#pragma unroll
      for (int r = 0; r < 16; ++r)
        Ocmb[qi * 2048 + (vt * 16 + r) * 64 + lane] = oacc[vt][r];
    Lcmb[qi * 64 + lane] = lpart;
  }
  __syncthreads();
  if (ki == 0) {
#pragma unroll
    for (int vt = 0; vt < 2; ++vt)
#pragma unroll
      for (int r = 0; r < 16; ++r)
        oacc[vt][r] += Ocmb[qi * 2048 + (vt * 16 + r) * 64 + lane];
    lpart += Lcmb[qi * 64 + lane];

    // lane-halves hold disjoint kv subsets of the same q
    lpart += __shfl_xor(lpart, 32);
    const float inv = 1.0f / lpart;

    // O^T C-layout: q = ln, d = vt*32 + g*8 + hf*4 + j; Og row-major [s][E]
    bf16* orow = Og + ((size_t)b * S + (size_t)tq * 32 + ln) * E + h * 64;
#pragma unroll
    for (int vt = 0; vt < 2; ++vt) {
#pragma unroll
      for (int g = 0; g < 4; ++g) {
        bf16x4 o;
#pragma unroll
        for (int j = 0; j < 4; ++j) o[j] = (bf16)(oacc[vt][g * 4 + j] * inv);
        *(bf16x4*)&orow[vt * 32 + g * 8 + hf * 4] = o;
      }
    }
  }
}

// ---------------------------------------------------------------------------
extern "C" void kernel_launch(void* const* d_in, const int* in_sizes, int n_in,
                              void* d_out, int out_size, void* d_ws, size_t ws_size,
                              hipStream_t stream) {
  const float* x = (const float*)d_in[0];
  const float* Wq = (const float*)d_in[1];
  const float* bq = (const float*)d_in[2];
  const float* Wk = (const float*)d_in[3];
  const float* bk = (const float*)d_in[4];
  const float* Wv = (const float*)d_in[5];
  const float* bv = (const float*)d_in[6];
  const float* Wo = (const float*)d_in[7];
  const float* bo = (const float*)d_in[8];

  const size_t ME = (size_t)4096 * 1024;  // 4M elems
  const size_t WE = (size_t)1024 * 1024;  // 1M elems
  bf16* xb = (bf16*)d_ws;
  bf16* wqt = xb + ME;
  bf16* wkt = wqt + WE;   // contiguous with wqt: fused B = [3072][1024]
  bf16* wvt = wkt + WE;
  bf16* wot = wvt + WE;
  bf16* qb = wot + WE;   // Q frags
  bf16* kb = qb + ME;    // K frags
  bf16* vt = kb + ME;    // V frags
  bf16* ab = vt + ME;    // attn out, row-major [B*S][E]

  cast_x<<<2048, 256, 0, stream>>>(x, xb);
  transpose_cast_w<<<dim3(16, 16, 4), 256, 0, stream>>>(Wq, Wk, Wv, Wo, wqt, wkt,
                                                        wvt, wot);
  gemm_qkv<<<dim3(12, 16), 512, 0, stream>>>(xb, wqt, bq, bk, bv, qb, kb, vt);
  attn_mfma<<<dim3(S / 128, H, 2), 512, 0, stream>>>(qb, kb, vt, ab);
  gemm_wo<<<dim3(8, 64), 256, 0, stream>>>(ab, wot, bo, (float*)d_out);
}

// Round 10
// 190.896 us; speedup vs baseline: 1.6237x; 1.0194x over previous
//
#include <hip/hip_runtime.h>
#include <math.h>
#include <stdint.h>

typedef __bf16 bf16;
typedef __bf16 bf16x2 __attribute__((ext_vector_type(2)));
typedef __bf16 bf16x4 __attribute__((ext_vector_type(4)));
typedef __bf16 bf16x8 __attribute__((ext_vector_type(8)));
typedef float f32x4 __attribute__((ext_vector_type(4)));
typedef float f32x16 __attribute__((ext_vector_type(16)));

constexpr int E = 1024;   // embed dim
constexpr int S = 2048;   // seq len
constexpr int H = 16;     // heads (Dh = 64)

// Fragment layouts (1KB blocks, lane l = hf*32 + ln, 16B per lane):
//  Q/K frag: per (b,h): block (t, c), t = s/32 (64), c = d-chunk/16 (4).
//    lane l = hf*32 + (s%32); bytes = X[s][c*16 + hf*8 + j], j=0..7.
//    elem addr = (bh*256 + t*4 + c)*512 + l*8 + j        (131072 elems per bh)
//  V frag: per (b,h): block (tau, mt, c), tau = s/64 (32), mt = d/32 (2),
//    c = s-chunk-in-tile/16 (4). lane l = hf*32 + (d%32);
//    bytes = V^T[d][tau*64 + c*16 + hf*8 + j].
//    elem addr = (bh*256 + tau*8 + mt*4 + c)*512 + l*8 + j

// async global->LDS, 16B per lane; LDS dst = wave-uniform base + lane*16
__device__ __forceinline__ void gload16(const void* g, void* l) {
  __builtin_amdgcn_global_load_lds(
      (__attribute__((address_space(1))) void*)(uintptr_t)g,
      (__attribute__((address_space(3))) void*)(uint32_t)(uintptr_t)l, 16, 0, 0);
}

__device__ __forceinline__ f32x4 mfma16(bf16x8 a, bf16x8 b, f32x4 c) {
  return __builtin_amdgcn_mfma_f32_16x16x32_bf16(a, b, c, 0, 0, 0);
}
__device__ __forceinline__ f32x16 mfma32(bf16x8 a, bf16x8 b, f32x16 c) {
  return __builtin_amdgcn_mfma_f32_32x32x16_bf16(a, b, c, 0, 0, 0);
}

// native 2^x: ONE v_exp_f32 (NOT exp2f -> libm bloat, R1's regression)
__device__ __forceinline__ float fexp2(float x) {
#if __has_builtin(__builtin_amdgcn_exp2f)
  return __builtin_amdgcn_exp2f(x);
#else
  float r;
  asm("v_exp_f32 %0, %1" : "=v"(r) : "v"(x));
  return r;
#endif
}

// pack 2 f32 -> u32 of 2 bf16
__device__ __forceinline__ uint32_t pkbf(float lo, float hi) {
  bf16x2 p;
  p[0] = (bf16)lo;
  p[1] = (bf16)hi;
  return __builtin_bit_cast(uint32_t, p);
}

// ---------------------------------------------------------------------------
// cast x (fp32) -> bf16, 8 elems/thread
// ---------------------------------------------------------------------------
__global__ __launch_bounds__(256) void cast_x(const float* __restrict__ x,
                                              bf16* __restrict__ o) {
  const size_t i = ((size_t)blockIdx.x * 256 + threadIdx.x) * 8;
  const float4 a = *(const float4*)(x + i);
  const float4 b = *(const float4*)(x + i + 4);
  bf16x8 r;
  r[0] = (bf16)a.x; r[1] = (bf16)a.y; r[2] = (bf16)a.z; r[3] = (bf16)a.w;
  r[4] = (bf16)b.x; r[5] = (bf16)b.y; r[6] = (bf16)b.z; r[7] = (bf16)b.w;
  *(bf16x8*)(o + i) = r;
}

// ---------------------------------------------------------------------------
// W[k][n] fp32 -> Wt[n][k] bf16 (all 4 weight matrices, blockIdx.z selects)
// ---------------------------------------------------------------------------
__global__ __launch_bounds__(256) void transpose_cast_w(
    const float* __restrict__ W0, const float* __restrict__ W1,
    const float* __restrict__ W2, const float* __restrict__ W3,
    bf16* __restrict__ T0, bf16* __restrict__ T1, bf16* __restrict__ T2,
    bf16* __restrict__ T3) {
  const float* W;
  bf16* T;
  switch (blockIdx.z) {
    case 0: W = W0; T = T0; break;
    case 1: W = W1; T = T1; break;
    case 2: W = W2; T = T2; break;
    default: W = W3; T = T3; break;
  }
  __shared__ float t[64][65];
  const int k0 = blockIdx.y * 64, n0 = blockIdx.x * 64;
  const int tr = threadIdx.x >> 4;          // 0..15
  const int tc = (threadIdx.x & 15) * 4;    // 0..60
#pragma unroll
  for (int u = 0; u < 4; ++u) {
    const float4 v = *(const float4*)(W + (size_t)(k0 + tr + u * 16) * E + n0 + tc);
    t[tr + u * 16][tc + 0] = v.x;
    t[tr + u * 16][tc + 1] = v.y;
    t[tr + u * 16][tc + 2] = v.z;
    t[tr + u * 16][tc + 3] = v.w;
  }
  __syncthreads();
#pragma unroll
  for (int u = 0; u < 4; ++u) {
    const int n = tr + u * 16;
    bf16x4 o;
#pragma unroll
    for (int i = 0; i < 4; ++i) o[i] = (bf16)t[tc + i][n];
    *(bf16x4*)(T + (size_t)(n0 + n) * E + k0 + tc) = o;
  }
}

// ---------------------------------------------------------------------------
// Fused QKV GEMM -> MFMA-frag-layout outputs (R5-proven m97-style; the
// 256^2 8-phase port was tried in R8/R9: conflict-free after the 3-bit
// swizzle fix but 48us vs this kernel's ~38-40 — at K=1024 / 192 blocks the
// 8-phase template loses 25% of CUs (1 blk/CU) and can't amortize its
// pipeline, so m97-style 3-blk/CU wins at THIS shape).
// z selects {Wq->Qf, Wk->Kf, Wv->Vf}. 128x128 tile, BK=32. z==0 scales by
// 0.125*log2(e) (softmax uses native exp2: 2^(s*log2e) == e^s).
// Grid (8, 32, 3) = 768 blocks = 3/CU.
// ---------------------------------------------------------------------------
__global__ __launch_bounds__(256) void gemm_qkv(const bf16* __restrict__ A,
                                                const bf16* __restrict__ Wt,
                                                const float* __restrict__ bq,
                                                const float* __restrict__ bk,
                                                const float* __restrict__ bv,
                                                bf16* __restrict__ qo,
                                                bf16* __restrict__ ko,
                                                bf16* __restrict__ vo) {
  __shared__ __attribute__((aligned(16))) bf16 Asm[128 * 32];
  __shared__ __attribute__((aligned(16))) bf16 Bsm[128 * 32];
  const int z = blockIdx.z;
  const bf16* Bt = Wt + (size_t)z * E * E;
  const float* bias = (z == 0) ? bq : (z == 1) ? bk : bv;
  const int tid = threadIdx.x;
  const int w = tid >> 6, lane = tid & 63, quad = lane >> 4, ln = lane & 15;
  const int bm = blockIdx.y * 128, bn = blockIdx.x * 128;
  const int wr = w >> 1, wc = w & 1;
  const int srow = w * 32 + (lane >> 2);
  const int scol = (lane & 3) * 8;
  const bf16* Ag = A + (size_t)(bm + srow) * E + scol;
  const bf16* Bg = Bt + (size_t)(bn + srow) * E + scol;
  f32x4 acc[4][4] = {};

  for (int k0 = 0; k0 < E; k0 += 32) {
    gload16(Ag + k0, &Asm[(w * 32) * 32]);
    gload16(Ag + k0 + (size_t)16 * E, &Asm[(w * 32 + 16) * 32]);
    gload16(Bg + k0, &Bsm[(w * 32) * 32]);
    gload16(Bg + k0 + (size_t)16 * E, &Bsm[(w * 32 + 16) * 32]);
    __syncthreads();
    bf16x8 af[4], bfr[4];
#pragma unroll
    for (int t = 0; t < 4; ++t) {
      af[t] = *(const bf16x8*)&Asm[(wr * 64 + t * 16 + ln) * 32 + quad * 8];
      bfr[t] = *(const bf16x8*)&Bsm[(wc * 64 + t * 16 + ln) * 32 + quad * 8];
    }
#pragma unroll
    for (int rt = 0; rt < 4; ++rt)
#pragma unroll
      for (int ct = 0; ct < 4; ++ct)
        acc[rt][ct] = mfma16(af[rt], bfr[ct], acc[rt][ct]);
    __syncthreads();
  }

  // 0.125 * log2(e) = 0.18033688011112042
  const float scl = (z == 0) ? 0.18033688f : 1.0f;
  const int hglob = (bn + wc * 64) >> 6;  // head (wave col-group = one head)
  float bvv[4];
#pragma unroll
  for (int ct = 0; ct < 4; ++ct) bvv[ct] = bias[bn + wc * 64 + ct * 16 + ln];

#pragma unroll
  for (int rt = 0; rt < 4; ++rt) {
    const int row0 = bm + wr * 64 + rt * 16 + quad * 4;
    const int bb = row0 >> 11;        // batch (tiles never span: 2048%128==0)
    const int rl = row0 & 2047;       // seq within batch
    const size_t hb = (size_t)(bb * 16 + hglob) * 131072;
#pragma unroll
    for (int ct = 0; ct < 4; ++ct) {
      if (z == 2) {
        // V frag: d = ct*16+ln -> mt = ct>>1, ln32 = (ct&1)*16+ln;
        // s = row0 -> tau = rl>>6, hf = (rl>>3)&1, j0 = rl&7 (r gives j0..j0+3)
        const int mt = ct >> 1, ln32 = ((ct & 1) << 4) | ln;
        const int tau = rl >> 6, hfv = (rl >> 3) & 1, j0 = rl & 7;
        bf16x4 p;
#pragma unroll
        for (int r = 0; r < 4; ++r) p[r] = (bf16)(acc[rt][ct][r] + bvv[ct]);
        *(bf16x4*)&vo[hb + (size_t)((tau * 8 + mt * 4 + rt) * 512 +
                                    hfv * 256 + ln32 * 8 + j0)] = p;
      } else {
        // Q/K frag: s -> t = rl>>5, ln0 = rl&31 (+r); d = ct*16+ln ->
        // c = ct, hf = ln>>3, j = ln&7
        bf16* o = (z == 0) ? qo : ko;
        const int t = rl >> 5, ln0 = rl & 31;
        const size_t base =
            hb + (size_t)((t * 4 + ct) * 512 + (ln >> 3) * 256 + (ln & 7));
#pragma unroll
        for (int r = 0; r < 4; ++r)
          o[base + (ln0 + r) * 8] = (bf16)((acc[rt][ct][r] + bvv[ct]) * scl);
      }
    }
  }
}

// ---------------------------------------------------------------------------
// Output GEMM: C[4096][1024] fp32 = A @ Wt^T + bias. 64x128 tile -> 512 blocks.
// ---------------------------------------------------------------------------
__global__ __launch_bounds__(256) void gemm_wo(const bf16* __restrict__ A,
                                               const bf16* __restrict__ Bt,
                                               const float* __restrict__ bias,
                                               float* __restrict__ C) {
  __shared__ __attribute__((aligned(16))) bf16 Asm[64 * 32];
  __shared__ __attribute__((aligned(16))) bf16 Bsm[128 * 32];
  const int tid = threadIdx.x;
  const int w = tid >> 6, lane = tid & 63, quad = lane >> 4, ln = lane & 15;
  const int bm = blockIdx.y * 64, bn = blockIdx.x * 128;
  const int wr = w >> 1, wc = w & 1;
  const int sr = lane >> 2, sc = (lane & 3) * 8;
  const bf16* Ag = A + (size_t)(bm + w * 16 + sr) * E + sc;
  const bf16* Bg = Bt + (size_t)(bn + w * 32 + sr) * E + sc;
  f32x4 acc[2][4] = {};

  for (int k0 = 0; k0 < E; k0 += 32) {
    gload16(Ag + k0, &Asm[(w * 16) * 32]);
    gload16(Bg + k0, &Bsm[(w * 32) * 32]);
    gload16(Bg + k0 + (size_t)16 * E, &Bsm[(w * 32 + 16) * 32]);
    __syncthreads();
    bf16x8 af[2], bfr[4];
#pragma unroll
    for (int t = 0; t < 2; ++t)
      af[t] = *(const bf16x8*)&Asm[(wr * 32 + t * 16 + ln) * 32 + quad * 8];
#pragma unroll
    for (int t = 0; t < 4; ++t)
      bfr[t] = *(const bf16x8*)&Bsm[(wc * 64 + t * 16 + ln) * 32 + quad * 8];
#pragma unroll
    for (int rt = 0; rt < 2; ++rt)
#pragma unroll
      for (int ct = 0; ct < 4; ++ct)
        acc[rt][ct] = mfma16(af[rt], bfr[ct], acc[rt][ct]);
    __syncthreads();
  }

  float bvv[4];
#pragma unroll
  for (int ct = 0; ct < 4; ++ct) bvv[ct] = bias[bn + wc * 64 + ct * 16 + ln];
#pragma unroll
  for (int rt = 0; rt < 2; ++rt) {
    const int row0 = bm + wr * 32 + rt * 16 + quad * 4;
#pragma unroll
    for (int ct = 0; ct < 4; ++ct) {
      const int c = bn + wc * 64 + ct * 16 + ln;
#pragma unroll
      for (int r = 0; r < 4; ++r)
        C[(size_t)(row0 + r) * E + c] = acc[rt][ct][r] + bvv[ct];
    }
  }
}

// ---------------------------------------------------------------------------
// MFMA flash attention v11 (R5, PROVEN 42.9us — structural optimum: 16
// waves/CU requires <=128 regs/wave which forces 1 q-group; R3/R6/R7 all
// regressed trying to leave this corner). Frozen.
// ---------------------------------------------------------------------------
__global__ __launch_bounds__(512, 4) void attn_mfma(const bf16* __restrict__ Qf,
                                                    const bf16* __restrict__ Kf,
                                                    const bf16* __restrict__ Vf,
                                                    bf16* __restrict__ Og) {
  // buffer b at smem + b*32768: [K: 2 ki x 4096 elems][V: 2 ki x 4096 elems]
  __shared__ __attribute__((aligned(16))) char smem[65536];

  const int tid = threadIdx.x;
  const int w = tid >> 6, lane = tid & 63, ln = lane & 31, hf = lane >> 5;
  const int qi = w & 3, ki = w >> 2;
  const int tq = blockIdx.x * 4 + qi;       // q-tile (32 q-rows)
  const int h = blockIdx.y, b = blockIdx.z;
  const size_t fb = (size_t)(b * H + h) * 131072;

  // Q B-frags once (B[k=d][n=q]): lane q = ln, d = c*16 + hf*8 + j
  bf16x8 qf[4];
  {
    const bf16* qb = Qf + fb + (size_t)tq * 2048 + lane * 8;
#pragma unroll
    for (int c = 0; c < 4; ++c) qf[c] = *(const bf16x8*)(qb + c * 512);
  }

  // staging: wave (qi,ki) copies chunks qi*2, qi*2+1 of its group's tile
  const bf16* Ksrc = Kf + fb + qi * 1024 + lane * 8;
  const bf16* Vsrc = Vf + fb + qi * 1024 + lane * 8;
  const int dstoff = ki * 4096 + qi * 1024;  // elems within a buffer's K or V

  float lpart = 0.f;
  f32x16 oacc[2] = {};

#define STAGE(i, buf)                                                  \
  do {                                                                 \
    const size_t toff = (size_t)(ki * 16 + (i)) * 4096;                \
    bf16* kd = (bf16*)(smem + (buf) * 32768) + dstoff;                 \
    bf16* vd = (bf16*)(smem + (buf) * 32768 + 16384) + dstoff;         \
    gload16(Ksrc + toff, kd);                                          \
    gload16(Ksrc + toff + 512, kd + 512);                              \
    gload16(Vsrc + toff, vd);                                          \
    gload16(Vsrc + toff + 512, vd + 512);                              \
  } while (0)

  STAGE(0, 0);
  __syncthreads();  // vmcnt(0)+barrier: tile 0 staged

#pragma unroll 2
  for (int i = 0; i < 16; ++i) {
    const int cur = i & 1;
    if (i < 15) STAGE(i + 1, cur ^ 1);  // prefetch: latency hides under MFMA
    const bf16* Ks = (const bf16*)(smem + cur * 32768) + ki * 4096;
    const bf16* Vs = (const bf16*)(smem + cur * 32768 + 16384) + ki * 4096;

#pragma unroll
    for (int mt = 0; mt < 2; ++mt) {
      // scores S^T (rows kv, cols q): A = K frags, B = qf
      f32x16 st = {};
      __builtin_amdgcn_s_setprio(1);
#pragma unroll
      for (int c = 0; c < 4; ++c)
        st = mfma32(*(const bf16x8*)&Ks[(mt * 4 + c) * 512 + lane * 8], qf[c],
                    st);
      __builtin_amdgcn_s_setprio(0);

      // P = 2^st (Q carries 0.125*log2e); C-layout kv = 8g + 4hf + j
      float pe[16];
#pragma unroll
      for (int r = 0; r < 16; ++r) pe[r] = fexp2(st[r]);
      // tree-reduce row-sum (short dep chain, not a 16-long serial fadd)
      lpart += (((pe[0] + pe[1]) + (pe[2] + pe[3])) +
                ((pe[4] + pe[5]) + (pe[6] + pe[7]))) +
               (((pe[8] + pe[9]) + (pe[10] + pe[11])) +
                ((pe[12] + pe[13]) + (pe[14] + pe[15])));

      // Build PV B-frags in-register (T12): one permlane32_swap fills two
      // words: swap(pk(g0:j0,j1), pk(g1:j0,j1)) -> word0 (j0,j1), word2.
      bf16x8 pb[2];
#pragma unroll
      for (int cl = 0; cl < 2; ++cl) {
        uint32_t a01 = pkbf(pe[cl * 8 + 0], pe[cl * 8 + 1]);
        uint32_t a23 = pkbf(pe[cl * 8 + 2], pe[cl * 8 + 3]);
        uint32_t b01 = pkbf(pe[cl * 8 + 4], pe[cl * 8 + 5]);
        uint32_t b23 = pkbf(pe[cl * 8 + 6], pe[cl * 8 + 7]);
        auto r0 = __builtin_amdgcn_permlane32_swap(a01, b01, false, false);
        auto r1 = __builtin_amdgcn_permlane32_swap(a23, b23, false, false);
        union {
          bf16x8 v;
          uint32_t u[4];
        } pu;
        pu.u[0] = r0[0];
        pu.u[1] = r1[0];
        pu.u[2] = r0[1];
        pu.u[3] = r1[1];
        pb[cl] = pu.v;
      }

      // O^T += V^T . P^T  (A = V frags, kv-chunk c = mt*2 + cl)
      __builtin_amdgcn_s_setprio(1);
#pragma unroll
      for (int vt = 0; vt < 2; ++vt) {
        oacc[vt] = mfma32(
            *(const bf16x8*)&Vs[(vt * 4 + mt * 2 + 0) * 512 + lane * 8], pb[0],
            oacc[vt]);
        oacc[vt] = mfma32(
            *(const bf16x8*)&Vs[(vt * 4 + mt * 2 + 1) * 512 + lane * 8], pb[1],
            oacc[vt]);
      }
      __builtin_amdgcn_s_setprio(0);
    }
    __syncthreads();  // reads retired + next tile's gloads drained (vmcnt 0)
  }
#undef STAGE

  // ---- kv-half combine (deferred softmax => partials just add) ----
  float* Ocmb = (float*)smem;            // 4 qi x 32 x 64 f32 = 32 KB
  float* Lcmb = (float*)(smem + 32768);  // 4 qi x 64 f32
  if (ki == 1) {
#pragma unroll
    for (int vt = 0; vt < 2; ++vt)
#pragma unroll
      for (int r = 0; r < 16; ++r)
        Ocmb[qi * 2048 + (vt * 16 + r) * 64 + lane] = oacc[vt][r];
    Lcmb[qi * 64 + lane] = lpart;
  }
  __syncthreads();
  if (ki == 0) {
#pragma unroll
    for (int vt = 0; vt < 2; ++vt)
#pragma unroll
      for (int r = 0; r < 16; ++r)
        oacc[vt][r] += Ocmb[qi * 2048 + (vt * 16 + r) * 64 + lane];
    lpart += Lcmb[qi * 64 + lane];

    // lane-halves hold disjoint kv subsets of the same q
    lpart += __shfl_xor(lpart, 32);
    const float inv = 1.0f / lpart;

    // O^T C-layout: q = ln, d = vt*32 + g*8 + hf*4 + j; Og row-major [s][E]
    bf16* orow = Og + ((size_t)b * S + (size_t)tq * 32 + ln) * E + h * 64;
#pragma unroll
    for (int vt = 0; vt < 2; ++vt) {
#pragma unroll
      for (int g = 0; g < 4; ++g) {
        bf16x4 o;
#pragma unroll
        for (int j = 0; j < 4; ++j) o[j] = (bf16)(oacc[vt][g * 4 + j] * inv);
        *(bf16x4*)&orow[vt * 32 + g * 8 + hf * 4] = o;
      }
    }
  }
}

// ---------------------------------------------------------------------------
extern "C" void kernel_launch(void* const* d_in, const int* in_sizes, int n_in,
                              void* d_out, int out_size, void* d_ws, size_t ws_size,
                              hipStream_t stream) {
  const float* x = (const float*)d_in[0];
  const float* Wq = (const float*)d_in[1];
  const float* bq = (const float*)d_in[2];
  const float* Wk = (const float*)d_in[3];
  const float* bk = (const float*)d_in[4];
  const float* Wv = (const float*)d_in[5];
  const float* bv = (const float*)d_in[6];
  const float* Wo = (const float*)d_in[7];
  const float* bo = (const float*)d_in[8];

  const size_t ME = (size_t)4096 * 1024;  // 4M elems
  const size_t WE = (size_t)1024 * 1024;  // 1M elems
  bf16* xb = (bf16*)d_ws;
  bf16* wqt = xb + ME;
  bf16* wkt = wqt + WE;
  bf16* wvt = wkt + WE;
  bf16* wot = wvt + WE;
  bf16* qb = wot + WE;   // Q frags
  bf16* kb = qb + ME;    // K frags
  bf16* vt = kb + ME;    // V frags
  bf16* ab = vt + ME;    // attn out, row-major [B*S][E]

  cast_x<<<2048, 256, 0, stream>>>(x, xb);
  transpose_cast_w<<<dim3(16, 16, 4), 256, 0, stream>>>(Wq, Wk, Wv, Wo, wqt, wkt,
                                                        wvt, wot);
  gemm_qkv<<<dim3(8, 32, 3), 256, 0, stream>>>(xb, wqt, bq, bk, bv, qb, kb, vt);
  attn_mfma<<<dim3(S / 128, H, 2), 512, 0, stream>>>(qb, kb, vt, ab);
  gemm_wo<<<dim3(8, 64), 256, 0, stream>>>(ab, wot, bo, (float*)d_out);
}

// Round 11
// 186.950 us; speedup vs baseline: 1.6580x; 1.0211x over previous
//
#include <hip/hip_runtime.h>
#include <math.h>
#include <stdint.h>

typedef __bf16 bf16;
typedef __bf16 bf16x2 __attribute__((ext_vector_type(2)));
typedef __bf16 bf16x4 __attribute__((ext_vector_type(4)));
typedef __bf16 bf16x8 __attribute__((ext_vector_type(8)));
typedef float f32x4 __attribute__((ext_vector_type(4)));
typedef float f32x16 __attribute__((ext_vector_type(16)));

constexpr int E = 1024;   // embed dim
constexpr int S = 2048;   // seq len
constexpr int H = 16;     // heads (Dh = 64)

// Fragment layouts (1KB blocks, lane l = hf*32 + ln, 16B per lane):
//  Q/K frag: per (b,h): block (t, c), t = s/32 (64), c = d-chunk/16 (4).
//    lane l = hf*32 + (s%32); bytes = X[s][c*16 + hf*8 + j], j=0..7.
//    elem addr = (bh*256 + t*4 + c)*512 + l*8 + j        (131072 elems per bh)
//  V frag: per (b,h): block (tau, mt, c), tau = s/64 (32), mt = d/32 (2),
//    c = s-chunk-in-tile/16 (4). lane l = hf*32 + (d%32);
//    bytes = V^T[d][tau*64 + c*16 + hf*8 + j].
//    elem addr = (bh*256 + tau*8 + mt*4 + c)*512 + l*8 + j

// async global->LDS, 16B per lane; LDS dst = wave-uniform base + lane*16
__device__ __forceinline__ void gload16(const void* g, void* l) {
  __builtin_amdgcn_global_load_lds(
      (__attribute__((address_space(1))) void*)(uintptr_t)g,
      (__attribute__((address_space(3))) void*)(uint32_t)(uintptr_t)l, 16, 0, 0);
}

__device__ __forceinline__ f32x4 mfma16(bf16x8 a, bf16x8 b, f32x4 c) {
  return __builtin_amdgcn_mfma_f32_16x16x32_bf16(a, b, c, 0, 0, 0);
}
__device__ __forceinline__ f32x16 mfma32(bf16x8 a, bf16x8 b, f32x16 c) {
  return __builtin_amdgcn_mfma_f32_32x32x16_bf16(a, b, c, 0, 0, 0);
}

// native 2^x: ONE v_exp_f32 (NOT exp2f -> libm bloat, R1's regression)
__device__ __forceinline__ float fexp2(float x) {
#if __has_builtin(__builtin_amdgcn_exp2f)
  return __builtin_amdgcn_exp2f(x);
#else
  float r;
  asm("v_exp_f32 %0, %1" : "=v"(r) : "v"(x));
  return r;
#endif
}

// pack 2 f32 -> u32 of 2 bf16
__device__ __forceinline__ uint32_t pkbf(float lo, float hi) {
  bf16x2 p;
  p[0] = (bf16)lo;
  p[1] = (bf16)hi;
  return __builtin_bit_cast(uint32_t, p);
}

// ---------------------------------------------------------------------------
// cast x (fp32) -> bf16, 8 elems/thread
// ---------------------------------------------------------------------------
__global__ __launch_bounds__(256) void cast_x(const float* __restrict__ x,
                                              bf16* __restrict__ o) {
  const size_t i = ((size_t)blockIdx.x * 256 + threadIdx.x) * 8;
  const float4 a = *(const float4*)(x + i);
  const float4 b = *(const float4*)(x + i + 4);
  bf16x8 r;
  r[0] = (bf16)a.x; r[1] = (bf16)a.y; r[2] = (bf16)a.z; r[3] = (bf16)a.w;
  r[4] = (bf16)b.x; r[5] = (bf16)b.y; r[6] = (bf16)b.z; r[7] = (bf16)b.w;
  *(bf16x8*)(o + i) = r;
}

// ---------------------------------------------------------------------------
// W[k][n] fp32 -> Wt[n][k] bf16 (all 4 weight matrices, blockIdx.z selects)
// ---------------------------------------------------------------------------
__global__ __launch_bounds__(256) void transpose_cast_w(
    const float* __restrict__ W0, const float* __restrict__ W1,
    const float* __restrict__ W2, const float* __restrict__ W3,
    bf16* __restrict__ T0, bf16* __restrict__ T1, bf16* __restrict__ T2,
    bf16* __restrict__ T3) {
  const float* W;
  bf16* T;
  switch (blockIdx.z) {
    case 0: W = W0; T = T0; break;
    case 1: W = W1; T = T1; break;
    case 2: W = W2; T = T2; break;
    default: W = W3; T = T3; break;
  }
  __shared__ float t[64][65];
  const int k0 = blockIdx.y * 64, n0 = blockIdx.x * 64;
  const int tr = threadIdx.x >> 4;          // 0..15
  const int tc = (threadIdx.x & 15) * 4;    // 0..60
#pragma unroll
  for (int u = 0; u < 4; ++u) {
    const float4 v = *(const float4*)(W + (size_t)(k0 + tr + u * 16) * E + n0 + tc);
    t[tr + u * 16][tc + 0] = v.x;
    t[tr + u * 16][tc + 1] = v.y;
    t[tr + u * 16][tc + 2] = v.z;
    t[tr + u * 16][tc + 3] = v.w;
  }
  __syncthreads();
#pragma unroll
  for (int u = 0; u < 4; ++u) {
    const int n = tr + u * 16;
    bf16x4 o;
#pragma unroll
    for (int i = 0; i < 4; ++i) o[i] = (bf16)t[tc + i][n];
    *(bf16x4*)(T + (size_t)(n0 + n) * E + k0 + tc) = o;
  }
}

// ---------------------------------------------------------------------------
// Fused QKV GEMM -> MFMA-frag-layout outputs (R5-proven m97-style; the
// 256^2 8-phase port was tried in R8/R9: conflict-free after the 3-bit
// swizzle fix but 48us vs this kernel's ~38-40 — at K=1024 / 192 blocks the
// 8-phase template loses 25% of CUs (1 blk/CU) and can't amortize its
// pipeline, so m97-style 3-blk/CU wins at THIS shape).
// z selects {Wq->Qf, Wk->Kf, Wv->Vf}. 128x128 tile, BK=32. z==0 scales by
// 0.125*log2(e) (softmax uses native exp2: 2^(s*log2e) == e^s).
// Grid (8, 32, 3) = 768 blocks = 3/CU.
// ---------------------------------------------------------------------------
__global__ __launch_bounds__(256) void gemm_qkv(const bf16* __restrict__ A,
                                                const bf16* __restrict__ Wt,
                                                const float* __restrict__ bq,
                                                const float* __restrict__ bk,
                                                const float* __restrict__ bv,
                                                bf16* __restrict__ qo,
                                                bf16* __restrict__ ko,
                                                bf16* __restrict__ vo) {
  __shared__ __attribute__((aligned(16))) bf16 Asm[128 * 32];
  __shared__ __attribute__((aligned(16))) bf16 Bsm[128 * 32];
  const int z = blockIdx.z;
  const bf16* Bt = Wt + (size_t)z * E * E;
  const float* bias = (z == 0) ? bq : (z == 1) ? bk : bv;
  const int tid = threadIdx.x;
  const int w = tid >> 6, lane = tid & 63, quad = lane >> 4, ln = lane & 15;
  const int bm = blockIdx.y * 128, bn = blockIdx.x * 128;
  const int wr = w >> 1, wc = w & 1;
  const int srow = w * 32 + (lane >> 2);
  const int scol = (lane & 3) * 8;
  const bf16* Ag = A + (size_t)(bm + srow) * E + scol;
  const bf16* Bg = Bt + (size_t)(bn + srow) * E + scol;
  f32x4 acc[4][4] = {};

  for (int k0 = 0; k0 < E; k0 += 32) {
    gload16(Ag + k0, &Asm[(w * 32) * 32]);
    gload16(Ag + k0 + (size_t)16 * E, &Asm[(w * 32 + 16) * 32]);
    gload16(Bg + k0, &Bsm[(w * 32) * 32]);
    gload16(Bg + k0 + (size_t)16 * E, &Bsm[(w * 32 + 16) * 32]);
    __syncthreads();
    bf16x8 af[4], bfr[4];
#pragma unroll
    for (int t = 0; t < 4; ++t) {
      af[t] = *(const bf16x8*)&Asm[(wr * 64 + t * 16 + ln) * 32 + quad * 8];
      bfr[t] = *(const bf16x8*)&Bsm[(wc * 64 + t * 16 + ln) * 32 + quad * 8];
    }
#pragma unroll
    for (int rt = 0; rt < 4; ++rt)
#pragma unroll
      for (int ct = 0; ct < 4; ++ct)
        acc[rt][ct] = mfma16(af[rt], bfr[ct], acc[rt][ct]);
    __syncthreads();
  }

  // 0.125 * log2(e) = 0.18033688011112042
  const float scl = (z == 0) ? 0.18033688f : 1.0f;
  const int hglob = (bn + wc * 64) >> 6;  // head (wave col-group = one head)
  float bvv[4];
#pragma unroll
  for (int ct = 0; ct < 4; ++ct) bvv[ct] = bias[bn + wc * 64 + ct * 16 + ln];

#pragma unroll
  for (int rt = 0; rt < 4; ++rt) {
    const int row0 = bm + wr * 64 + rt * 16 + quad * 4;
    const int bb = row0 >> 11;        // batch (tiles never span: 2048%128==0)
    const int rl = row0 & 2047;       // seq within batch
    const size_t hb = (size_t)(bb * 16 + hglob) * 131072;
#pragma unroll
    for (int ct = 0; ct < 4; ++ct) {
      if (z == 2) {
        // V frag: d = ct*16+ln -> mt = ct>>1, ln32 = (ct&1)*16+ln;
        // s = row0 -> tau = rl>>6, hf = (rl>>3)&1, j0 = rl&7 (r gives j0..j0+3)
        const int mt = ct >> 1, ln32 = ((ct & 1) << 4) | ln;
        const int tau = rl >> 6, hfv = (rl >> 3) & 1, j0 = rl & 7;
        bf16x4 p;
#pragma unroll
        for (int r = 0; r < 4; ++r) p[r] = (bf16)(acc[rt][ct][r] + bvv[ct]);
        *(bf16x4*)&vo[hb + (size_t)((tau * 8 + mt * 4 + rt) * 512 +
                                    hfv * 256 + ln32 * 8 + j0)] = p;
      } else {
        // Q/K frag: s -> t = rl>>5, ln0 = rl&31 (+r); d = ct*16+ln ->
        // c = ct, hf = ln>>3, j = ln&7
        bf16* o = (z == 0) ? qo : ko;
        const int t = rl >> 5, ln0 = rl & 31;
        const size_t base =
            hb + (size_t)((t * 4 + ct) * 512 + (ln >> 3) * 256 + (ln & 7));
#pragma unroll
        for (int r = 0; r < 4; ++r)
          o[base + (ln0 + r) * 8] = (bf16)((acc[rt][ct][r] + bvv[ct]) * scl);
      }
    }
  }
}

// ---------------------------------------------------------------------------
// Output GEMM: C[4096][1024] fp32 = A @ Wt^T + bias. 64x128 tile -> 512 blocks.
// ---------------------------------------------------------------------------
__global__ __launch_bounds__(256) void gemm_wo(const bf16* __restrict__ A,
                                               const bf16* __restrict__ Bt,
                                               const float* __restrict__ bias,
                                               float* __restrict__ C) {
  __shared__ __attribute__((aligned(16))) bf16 Asm[64 * 32];
  __shared__ __attribute__((aligned(16))) bf16 Bsm[128 * 32];
  const int tid = threadIdx.x;
  const int w = tid >> 6, lane = tid & 63, quad = lane >> 4, ln = lane & 15;
  const int bm = blockIdx.y * 64, bn = blockIdx.x * 128;
  const int wr = w >> 1, wc = w & 1;
  const int sr = lane >> 2, sc = (lane & 3) * 8;
  const bf16* Ag = A + (size_t)(bm + w * 16 + sr) * E + sc;
  const bf16* Bg = Bt + (size_t)(bn + w * 32 + sr) * E + sc;
  f32x4 acc[2][4] = {};

  for (int k0 = 0; k0 < E; k0 += 32) {
    gload16(Ag + k0, &Asm[(w * 16) * 32]);
    gload16(Bg + k0, &Bsm[(w * 32) * 32]);
    gload16(Bg + k0 + (size_t)16 * E, &Bsm[(w * 32 + 16) * 32]);
    __syncthreads();
    bf16x8 af[2], bfr[4];
#pragma unroll
    for (int t = 0; t < 2; ++t)
      af[t] = *(const bf16x8*)&Asm[(wr * 32 + t * 16 + ln) * 32 + quad * 8];
#pragma unroll
    for (int t = 0; t < 4; ++t)
      bfr[t] = *(const bf16x8*)&Bsm[(wc * 64 + t * 16 + ln) * 32 + quad * 8];
#pragma unroll
    for (int rt = 0; rt < 2; ++rt)
#pragma unroll
      for (int ct = 0; ct < 4; ++ct)
        acc[rt][ct] = mfma16(af[rt], bfr[ct], acc[rt][ct]);
    __syncthreads();
  }

  float bvv[4];
#pragma unroll
  for (int ct = 0; ct < 4; ++ct) bvv[ct] = bias[bn + wc * 64 + ct * 16 + ln];
#pragma unroll
  for (int rt = 0; rt < 2; ++rt) {
    const int row0 = bm + wr * 32 + rt * 16 + quad * 4;
#pragma unroll
    for (int ct = 0; ct < 4; ++ct) {
      const int c = bn + wc * 64 + ct * 16 + ln;
#pragma unroll
      for (int r = 0; r < 4; ++r)
        C[(size_t)(row0 + r) * E + c] = acc[rt][ct][r] + bvv[ct];
    }
  }
}

// ---------------------------------------------------------------------------
// MFMA flash attention v11 + T1 XCD-locality grid decode (R11).
// Inner loop FROZEN (R5-proven 42.9us; R3/R4/R6/R7 regressions mapped the
// structural optimum). New: 1-D 512-block grid with id&31 = (h,b) group so
// the 16 blocks sharing one 512KB K/V panel all have id = grp (mod 8) ->
// same XCD under round-robin dispatch -> KV panel lives in ONE private L2
// (4 groups x 512KB = 2MB per XCD, fits 4MB). Cuts the global_load_lds
// drain latency (L2-hit ~200cy vs L3/remote 600+). Perf heuristic only —
// correctness independent of XCD mapping (G16).
// ---------------------------------------------------------------------------
__global__ __launch_bounds__(512, 4) void attn_mfma(const bf16* __restrict__ Qf,
                                                    const bf16* __restrict__ Kf,
                                                    const bf16* __restrict__ Vf,
                                                    bf16* __restrict__ Og) {
  // buffer b at smem + b*32768: [K: 2 ki x 4096 elems][V: 2 ki x 4096 elems]
  __shared__ __attribute__((aligned(16))) char smem[65536];

  const int tid = threadIdx.x;
  const int w = tid >> 6, lane = tid & 63, ln = lane & 31, hf = lane >> 5;
  const int qi = w & 3, ki = w >> 2;
  // XCD-locality decode: grp = id&31 -> same XCD for all 16 q-chunk blocks
  const int id = blockIdx.x;
  const int grp = id & 31;
  const int h = grp & 15, b = grp >> 4;
  const int qc = id >> 5;                   // q-chunk 0..15
  const int tq = qc * 4 + qi;               // q-tile (32 q-rows)
  const size_t fb = (size_t)(b * H + h) * 131072;

  // Q B-frags once (B[k=d][n=q]): lane q = ln, d = c*16 + hf*8 + j
  bf16x8 qf[4];
  {
    const bf16* qb = Qf + fb + (size_t)tq * 2048 + lane * 8;
#pragma unroll
    for (int c = 0; c < 4; ++c) qf[c] = *(const bf16x8*)(qb + c * 512);
  }

  // staging: wave (qi,ki) copies chunks qi*2, qi*2+1 of its group's tile
  const bf16* Ksrc = Kf + fb + qi * 1024 + lane * 8;
  const bf16* Vsrc = Vf + fb + qi * 1024 + lane * 8;
  const int dstoff = ki * 4096 + qi * 1024;  // elems within a buffer's K or V

  float lpart = 0.f;
  f32x16 oacc[2] = {};

#define STAGE(i, buf)                                                  \
  do {                                                                 \
    const size_t toff = (size_t)(ki * 16 + (i)) * 4096;                \
    bf16* kd = (bf16*)(smem + (buf) * 32768) + dstoff;                 \
    bf16* vd = (bf16*)(smem + (buf) * 32768 + 16384) + dstoff;         \
    gload16(Ksrc + toff, kd);                                          \
    gload16(Ksrc + toff + 512, kd + 512);                              \
    gload16(Vsrc + toff, vd);                                          \
    gload16(Vsrc + toff + 512, vd + 512);                              \
  } while (0)

  STAGE(0, 0);
  __syncthreads();  // vmcnt(0)+barrier: tile 0 staged

#pragma unroll 2
  for (int i = 0; i < 16; ++i) {
    const int cur = i & 1;
    if (i < 15) STAGE(i + 1, cur ^ 1);  // prefetch: latency hides under MFMA
    const bf16* Ks = (const bf16*)(smem + cur * 32768) + ki * 4096;
    const bf16* Vs = (const bf16*)(smem + cur * 32768 + 16384) + ki * 4096;

#pragma unroll
    for (int mt = 0; mt < 2; ++mt) {
      // scores S^T (rows kv, cols q): A = K frags, B = qf
      f32x16 st = {};
      __builtin_amdgcn_s_setprio(1);
#pragma unroll
      for (int c = 0; c < 4; ++c)
        st = mfma32(*(const bf16x8*)&Ks[(mt * 4 + c) * 512 + lane * 8], qf[c],
                    st);
      __builtin_amdgcn_s_setprio(0);

      // P = 2^st (Q carries 0.125*log2e); C-layout kv = 8g + 4hf + j
      float pe[16];
#pragma unroll
      for (int r = 0; r < 16; ++r) pe[r] = fexp2(st[r]);
      // tree-reduce row-sum (short dep chain, not a 16-long serial fadd)
      lpart += (((pe[0] + pe[1]) + (pe[2] + pe[3])) +
                ((pe[4] + pe[5]) + (pe[6] + pe[7]))) +
               (((pe[8] + pe[9]) + (pe[10] + pe[11])) +
                ((pe[12] + pe[13]) + (pe[14] + pe[15])));

      // Build PV B-frags in-register (T12): one permlane32_swap fills two
      // words: swap(pk(g0:j0,j1), pk(g1:j0,j1)) -> word0 (j0,j1), word2.
      bf16x8 pb[2];
#pragma unroll
      for (int cl = 0; cl < 2; ++cl) {
        uint32_t a01 = pkbf(pe[cl * 8 + 0], pe[cl * 8 + 1]);
        uint32_t a23 = pkbf(pe[cl * 8 + 2], pe[cl * 8 + 3]);
        uint32_t b01 = pkbf(pe[cl * 8 + 4], pe[cl * 8 + 5]);
        uint32_t b23 = pkbf(pe[cl * 8 + 6], pe[cl * 8 + 7]);
        auto r0 = __builtin_amdgcn_permlane32_swap(a01, b01, false, false);
        auto r1 = __builtin_amdgcn_permlane32_swap(a23, b23, false, false);
        union {
          bf16x8 v;
          uint32_t u[4];
        } pu;
        pu.u[0] = r0[0];
        pu.u[1] = r1[0];
        pu.u[2] = r0[1];
        pu.u[3] = r1[1];
        pb[cl] = pu.v;
      }

      // O^T += V^T . P^T  (A = V frags, kv-chunk c = mt*2 + cl)
      __builtin_amdgcn_s_setprio(1);
#pragma unroll
      for (int vt = 0; vt < 2; ++vt) {
        oacc[vt] = mfma32(
            *(const bf16x8*)&Vs[(vt * 4 + mt * 2 + 0) * 512 + lane * 8], pb[0],
            oacc[vt]);
        oacc[vt] = mfma32(
            *(const bf16x8*)&Vs[(vt * 4 + mt * 2 + 1) * 512 + lane * 8], pb[1],
            oacc[vt]);
      }
      __builtin_amdgcn_s_setprio(0);
    }
    __syncthreads();  // reads retired + next tile's gloads drained (vmcnt 0)
  }
#undef STAGE

  // ---- kv-half combine (deferred softmax => partials just add) ----
  float* Ocmb = (float*)smem;            // 4 qi x 32 x 64 f32 = 32 KB
  float* Lcmb = (float*)(smem + 32768);  // 4 qi x 64 f32
  if (ki == 1) {
#pragma unroll
    for (int vt = 0; vt < 2; ++vt)
#pragma unroll
      for (int r = 0; r < 16; ++r)
        Ocmb[qi * 2048 + (vt * 16 + r) * 64 + lane] = oacc[vt][r];
    Lcmb[qi * 64 + lane] = lpart;
  }
  __syncthreads();
  if (ki == 0) {
#pragma unroll
    for (int vt = 0; vt < 2; ++vt)
#pragma unroll
      for (int r = 0; r < 16; ++r)
        oacc[vt][r] += Ocmb[qi * 2048 + (vt * 16 + r) * 64 + lane];
    lpart += Lcmb[qi * 64 + lane];

    // lane-halves hold disjoint kv subsets of the same q
    lpart += __shfl_xor(lpart, 32);
    const float inv = 1.0f / lpart;

    // O^T C-layout: q = ln, d = vt*32 + g*8 + hf*4 + j; Og row-major [s][E]
    bf16* orow = Og + ((size_t)b * S + (size_t)tq * 32 + ln) * E + h * 64;
#pragma unroll
    for (int vt = 0; vt < 2; ++vt) {
#pragma unroll
      for (int g = 0; g < 4; ++g) {
        bf16x4 o;
#pragma unroll
        for (int j = 0; j < 4; ++j) o[j] = (bf16)(oacc[vt][g * 4 + j] * inv);
        *(bf16x4*)&orow[vt * 32 + g * 8 + hf * 4] = o;
      }
    }
  }
}

// ---------------------------------------------------------------------------
extern "C" void kernel_launch(void* const* d_in, const int* in_sizes, int n_in,
                              void* d_out, int out_size, void* d_ws, size_t ws_size,
                              hipStream_t stream) {
  const float* x = (const float*)d_in[0];
  const float* Wq = (const float*)d_in[1];
  const float* bq = (const float*)d_in[2];
  const float* Wk = (const float*)d_in[3];
  const float* bk = (const float*)d_in[4];
  const float* Wv = (const float*)d_in[5];
  const float* bv = (const float*)d_in[6];
  const float* Wo = (const float*)d_in[7];
  const float* bo = (const float*)d_in[8];

  const size_t ME = (size_t)4096 * 1024;  // 4M elems
  const size_t WE = (size_t)1024 * 1024;  // 1M elems
  bf16* xb = (bf16*)d_ws;
  bf16* wqt = xb + ME;
  bf16* wkt = wqt + WE;
  bf16* wvt = wkt + WE;
  bf16* wot = wvt + WE;
  bf16* qb = wot + WE;   // Q frags
  bf16* kb = qb + ME;    // K frags
  bf16* vt = kb + ME;    // V frags
  bf16* ab = vt + ME;    // attn out, row-major [B*S][E]

  cast_x<<<2048, 256, 0, stream>>>(x, xb);
  transpose_cast_w<<<dim3(16, 16, 4), 256, 0, stream>>>(Wq, Wk, Wv, Wo, wqt, wkt,
                                                        wvt, wot);
  gemm_qkv<<<dim3(8, 32, 3), 256, 0, stream>>>(xb, wqt, bq, bk, bv, qb, kb, vt);
  attn_mfma<<<512, 512, 0, stream>>>(qb, kb, vt, ab);
  gemm_wo<<<dim3(8, 64), 256, 0, stream>>>(ab, wot, bo, (float*)d_out);
}